// Round 6
// baseline (691.595 us; speedup 1.0000x reference)
//
#include <hip/hip_runtime.h>

typedef unsigned short u16;
typedef unsigned int u32;
typedef __attribute__((ext_vector_type(8))) short bf16x8;
typedef __attribute__((ext_vector_type(4))) float f32x4;

#define B_ 2
#define L_ 4096
#define HS_ 2048
#define NH_ 16
#define HD_ 128
#define FD_ 256

__device__ __forceinline__ float bf2f(u16 u) { return __uint_as_float(((u32)u) << 16); }
__device__ __forceinline__ u16 f2bf(float f) {
    u32 x = __float_as_uint(f);
    return (u16)((x + 0x7fffu + ((x >> 16) & 1u)) >> 16);
}

// async global->LDS, 16B per lane; LDS dest = wave-uniform base + lane*16
__device__ __forceinline__ void llds16(const u16* g, u16* l) {
    __builtin_amdgcn_global_load_lds((const __attribute__((address_space(1))) void*)g,
                                     (__attribute__((address_space(3))) void*)l, 16, 0, 0);
}

// ---------------------------------------------------------------------------
// Shared MFMA mainloop: C[128x128] block, 4 waves (2x2), 16x16x32 bf16 MFMA.
// A: [M,K] row-major bf16. Bt: [N,K] row-major bf16. LDS tiles [128][32].
// A-frag: A[m=lane&15][k=(lane>>4)*8+j]; D-frag: D[m=(lane>>4)*4+r][n=lane&15]
// (used by the kv gemm)
// ---------------------------------------------------------------------------
__device__ __forceinline__ void gemm_mainloop(const u16* __restrict__ Ab, int lda,
                                              const u16* __restrict__ Bb, int ldb,
                                              int K, u16* As, u16* Bs, f32x4 (&acc)[4][4]) {
    const int tid  = threadIdx.x;
    const int lane = tid & 63;
    const int wave = tid >> 6;
    const int wm = wave >> 1, wn = wave & 1;

    f32x4 zero = {0.f, 0.f, 0.f, 0.f};
#pragma unroll
    for (int i = 0; i < 4; i++)
#pragma unroll
        for (int j = 0; j < 4; j++) acc[i][j] = zero;

    const int srow = lane >> 2;
    const int scol = (lane & 3) * 8;
    const u16* pa = Ab + (size_t)(wave * 32 + srow) * lda + scol;
    const u16* pb = Bb + (size_t)(wave * 32 + srow) * ldb + scol;
    u16* la = As + wave * 1024;
    u16* lb = Bs + wave * 1024;

    const int arow = (wm * 64 + (lane & 15)) * 32 + (lane >> 4) * 8;
    const int brow = (wn * 64 + (lane & 15)) * 32 + (lane >> 4) * 8;

    for (int k0 = 0; k0 < K; k0 += 32) {
        llds16(pa, la);
        llds16(pa + 16 * lda, la + 512);
        llds16(pb, lb);
        llds16(pb + 16 * ldb, lb + 512);
        pa += 32; pb += 32;
        __syncthreads();
        bf16x8 af[4], bg[4];
#pragma unroll
        for (int mt = 0; mt < 4; mt++) af[mt] = *(const bf16x8*)(As + arow + mt * 512);
#pragma unroll
        for (int nt = 0; nt < 4; nt++) bg[nt] = *(const bf16x8*)(Bs + brow + nt * 512);
#pragma unroll
        for (int mt = 0; mt < 4; mt++)
#pragma unroll
            for (int nt = 0; nt < 4; nt++)
                acc[mt][nt] = __builtin_amdgcn_mfma_f32_16x16x32_bf16(af[mt], bg[nt], acc[mt][nt], 0, 0, 0);
        __syncthreads();
    }
}

// ---------------------------------------------------------------------------
// fp32 -> bf16 bulk convert (hidden_states -> Xbf). n multiple of 2048.
// ---------------------------------------------------------------------------
__global__ __launch_bounds__(256) void k_cvt(const float* __restrict__ src, u16* __restrict__ dst) {
    size_t i = ((size_t)blockIdx.x * 256 + threadIdx.x) * 8;
    float4 a = *(const float4*)(src + i);
    float4 b = *(const float4*)(src + i + 4);
    union { u16 h[8]; uint4 v; } o;
    o.h[0] = f2bf(a.x); o.h[1] = f2bf(a.y); o.h[2] = f2bf(a.z); o.h[3] = f2bf(a.w);
    o.h[4] = f2bf(b.x); o.h[5] = f2bf(b.y); o.h[6] = f2bf(b.z); o.h[7] = f2bf(b.w);
    *(uint4*)(dst + i) = o.v;
}

// ---------------------------------------------------------------------------
// Weight transposes + fp32->bf16: W[k][n] fp32 -> Wt[n][k] bf16
// ---------------------------------------------------------------------------
__global__ __launch_bounds__(256) void k_transpose(const float* Wq, const float* Wk, const float* Wv,
                                                   const float* Wo, const float* Wf1, const float* Wf2,
                                                   u16* Wqkv_t, u16* Wo_t, u16* Wf1_t, u16* Wf2_t) {
    const float* src; u16* dst; int R, C;
    switch (blockIdx.z) {
        case 0: src = Wq;  dst = Wqkv_t;                R = 2048; C = 2048; break;
        case 1: src = Wk;  dst = Wqkv_t + 2048 * 2048;  R = 2048; C = 2048; break;
        case 2: src = Wv;  dst = Wqkv_t + 2 * 2048 * 2048; R = 2048; C = 2048; break;
        case 3: src = Wo;  dst = Wo_t;                  R = 2048; C = 2048; break;
        case 4: src = Wf1; dst = Wf1_t;                 R = 128;  C = 256;  break;
        default: src = Wf2; dst = Wf2_t;                R = 256;  C = 256;  break;
    }
    int c0 = blockIdx.x * 32, r0 = blockIdx.y * 32;
    if (c0 >= C || r0 >= R) return;
    __shared__ u16 tile[32][33];
    int tx = threadIdx.x, ty = threadIdx.y;
    for (int i = ty; i < 32; i += 8) tile[i][tx] = f2bf(src[(size_t)(r0 + i) * C + c0 + tx]);
    __syncthreads();
    for (int i = ty; i < 32; i += 8) dst[(size_t)(c0 + i) * R + r0 + tx] = tile[tx][i];
}

// ---------------------------------------------------------------------------
// 256x256 8-phase mainloop template (T1+T2+T3+T4+T5), K=2048, stride 2048.
// (unchanged — see round-1 comments for the schedule derivation)
// ---------------------------------------------------------------------------
#define QKV_BAR() { __builtin_amdgcn_sched_barrier(0); __builtin_amdgcn_s_barrier(); \
                    __builtin_amdgcn_sched_barrier(0); }
#define QKV_LGKM0() { asm volatile("s_waitcnt lgkmcnt(0)" ::: "memory"); \
                      __builtin_amdgcn_sched_barrier(0); }

__device__ __forceinline__ void mainloop256(const u16* __restrict__ Abase,
                                            const u16* __restrict__ Bbase,
                                            u16* LDS, f32x4 (&acc)[8][4]) {
    const int tid = threadIdx.x, lane = tid & 63, wave = tid >> 6;
    const int wm = wave >> 2, wn = wave & 3;

    // staging source coords (inverse st_16x32 swizzle). Half-tile = 128x64 bf16
    // = 16 subtiles of [16 rows][32 cols] (1024B). j=0 -> subtiles 0-7, j=1 -> 8-15.
    int r0g, c0g, r1g, c1g;
    { int p = tid * 16; int s = p >> 10, q = p & 1023; q ^= ((q >> 9) & 1) << 5;
      r0g = (s >> 1) * 16 + (q >> 6); c0g = (s & 1) * 32 + ((q & 63) >> 1); }
    { int p = 8192 + tid * 16; int s = p >> 10, q = p & 1023; q ^= ((q >> 9) & 1) << 5;
      r1g = (s >> 1) * 16 + (q >> 6); c1g = (s & 1) * 32 + ((q & 63) >> 1); }
    const int voff0 = r0g * HS_ + c0g;
    const int voff1 = r1g * HS_ + c1g;

    // read-side swizzled in-subtile offset (u16 units): row=lane&15, 16B chunk=(lane>>4)
    int qby = (lane & 15) * 64 + (lane >> 4) * 16;
    qby ^= ((qby >> 9) & 1) << 5;
    const int qh = qby >> 1;

#define STG(G, soff, dstu) { \
    llds16((G) + (soff) + voff0, LDS + (dstu) + wave * 512); \
    llds16((G) + (soff) + voff1, LDS + (dstu) + 4096 + wave * 512); }

    const size_t a0 = 0, a1 = (size_t)128 * HS_;
    const size_t b0 = 0, b1 = (size_t)128 * HS_;

    // prologue: tile0 {B0,B1,A0,A1} + tile1 {B0,B1,A0}; A1(1) staged at t=0 P1.
    STG(Bbase, b0, 32768); STG(Bbase, b1, 40960);
    STG(Abase, a0, 0);     STG(Abase, a1, 8192);
    STG(Bbase, b0 + 64, 49152); STG(Bbase, b1 + 64, 57344);
    STG(Abase, a0 + 64, 16384);
    asm volatile("s_waitcnt vmcnt(6)" ::: "memory");   // tile0 complete
    QKV_BAR();

    f32x4 zero = {0.f, 0.f, 0.f, 0.f};
#pragma unroll
    for (int i = 0; i < 8; i++)
#pragma unroll
        for (int j = 0; j < 4; j++) acc[i][j] = zero;

    const int NT = HS_ / 64;   // 32
    bf16x8 afr[4][2], bfr[4][2];
    for (int t = 0; t < NT; t++) {
        const int bsel = t & 1;
        const u16* Ah = LDS + bsel * 16384 + wm * 8192;
        const u16* Bh = LDS + 32768 + bsel * 16384 + (wn >> 1) * 8192;
        const int bg0 = (wn & 1) * 4;
        const size_t kc1 = (size_t)(t + 1) * 64, kc2 = (size_t)(t + 2) * 64;

        // ---- phase 1 ----
#pragma unroll
        for (int mf = 0; mf < 4; mf++)
#pragma unroll
            for (int ks = 0; ks < 2; ks++)
                afr[mf][ks] = *(const bf16x8*)(Ah + (mf * 2 + ks) * 512 + qh);
#pragma unroll
        for (int nf = 0; nf < 4; nf++)
#pragma unroll
            for (int ks = 0; ks < 2; ks++)
                bfr[nf][ks] = *(const bf16x8*)(Bh + ((bg0 + nf) * 2 + ks) * 512 + qh);
        if (t + 1 < NT) STG(Abase, a1 + kc1, (bsel ^ 1) * 16384 + 8192);    // A1(t+1)
        QKV_BAR();
        QKV_LGKM0();
        __builtin_amdgcn_s_setprio(1);
#pragma unroll
        for (int mf = 0; mf < 4; mf++)
#pragma unroll
            for (int nf = 0; nf < 2; nf++)
#pragma unroll
                for (int ks = 0; ks < 2; ks++)
                    acc[mf][nf] = __builtin_amdgcn_mfma_f32_16x16x32_bf16(afr[mf][ks], bfr[nf][ks], acc[mf][nf], 0, 0, 0);
        __builtin_amdgcn_s_setprio(0);
        QKV_BAR();
        // ---- phase 2 ----
        if (t + 2 < NT) STG(Bbase, b0 + kc2, 32768 + bsel * 16384);        // B0(t+2)
        QKV_BAR();
        __builtin_amdgcn_s_setprio(1);
#pragma unroll
        for (int mf = 0; mf < 4; mf++)
#pragma unroll
            for (int nf = 2; nf < 4; nf++)
#pragma unroll
                for (int ks = 0; ks < 2; ks++)
                    acc[mf][nf] = __builtin_amdgcn_mfma_f32_16x16x32_bf16(afr[mf][ks], bfr[nf][ks], acc[mf][nf], 0, 0, 0);
        __builtin_amdgcn_s_setprio(0);
        QKV_BAR();
        // ---- phase 3 ----
#pragma unroll
        for (int mf = 0; mf < 4; mf++)
#pragma unroll
            for (int ks = 0; ks < 2; ks++)
                afr[mf][ks] = *(const bf16x8*)(Ah + ((mf + 4) * 2 + ks) * 512 + qh);
        if (t + 2 < NT) STG(Bbase, b1 + kc2, 32768 + bsel * 16384 + 8192); // B1(t+2)
        QKV_BAR();
        QKV_LGKM0();
        __builtin_amdgcn_s_setprio(1);
#pragma unroll
        for (int mf = 0; mf < 4; mf++)
#pragma unroll
            for (int nf = 0; nf < 2; nf++)
#pragma unroll
                for (int ks = 0; ks < 2; ks++)
                    acc[mf + 4][nf] = __builtin_amdgcn_mfma_f32_16x16x32_bf16(afr[mf][ks], bfr[nf][ks], acc[mf + 4][nf], 0, 0, 0);
        __builtin_amdgcn_s_setprio(0);
        QKV_BAR();
        // ---- phase 4 ----
        if (t + 2 < NT) STG(Abase, a0 + kc2, bsel * 16384);                 // A0(t+2)
        QKV_BAR();
        __builtin_amdgcn_s_setprio(1);
#pragma unroll
        for (int mf = 0; mf < 4; mf++)
#pragma unroll
            for (int nf = 2; nf < 4; nf++)
#pragma unroll
                for (int ks = 0; ks < 2; ks++)
                    acc[mf + 4][nf] = __builtin_amdgcn_mfma_f32_16x16x32_bf16(afr[mf][ks], bfr[nf][ks], acc[mf + 4][nf], 0, 0, 0);
        __builtin_amdgcn_s_setprio(0);
        if (t + 2 < NT) { asm volatile("s_waitcnt vmcnt(6)" ::: "memory"); }
        else if (t + 1 < NT) { asm volatile("s_waitcnt vmcnt(0)" ::: "memory"); }
        QKV_BAR();
    }
#undef STG
}

// ---------------------------------------------------------------------------
// QKV gemm: Xbf[8192,2048] @ Wqkv_t[6144,2048]^T + bias ->
//   q,k:[bh][l][d], vT:[bh][d][l]; bijective XCD chunking (4m x 24n / XCD).
// ---------------------------------------------------------------------------
__global__ __launch_bounds__(512, 2) void k_gemm_qkv(
        const u16* __restrict__ X, const u16* __restrict__ Wt,
        const float* __restrict__ bq, const float* __restrict__ bk, const float* __restrict__ bv,
        u16* __restrict__ qout, u16* __restrict__ kout, u16* __restrict__ vT) {
    __shared__ u16 LDS[65536];                 // 128 KB: A bufs [0,32768), B bufs [32768,65536)
    const int tid = threadIdx.x, lane = tid & 63, wave = tid >> 6;
    const int wm = wave >> 2, wn = wave & 3;

    // bijective XCD chunking: 768 blocks = 8 XCDs x (24 n x 4 m)
    const int xcd = blockIdx.x & 7, idx = blockIdx.x >> 3;
    const int nblk = idx >> 2;                 // 0..23
    const int mblk = xcd * 4 + (idx & 3);      // 0..31
    const int mb = mblk * 256, nb = nblk * 256;

    f32x4 acc[8][4];
    mainloop256(X + (size_t)mb * HS_, Wt + (size_t)nb * HS_, LDS, acc);

    // ---- epilogue: LDS-bounce, 2 half-passes (rows 0-127 / 128-255) ----
    const int which = nblk >> 3;                 // 0=q,1=k,2=v
    const int colbase = (nblk & 7) * 256;        // column within the 2048-wide output
    const int bi = mb >> 12, lb = mb & 4095;
    const float* bias = (which == 0) ? bq : (which == 1 ? bk : bv);
    const int rb = (lane >> 4) << 2, cl = lane & 15;

    if (which < 2) {
        u16* dst = (which == 0) ? qout : kout;
        const int bh0 = bi * NH_ + (colbase >> 7);
        for (int half = 0; half < 2; half++) {
            if (wm == half) {
#pragma unroll
                for (int nf = 0; nf < 4; nf++) {
                    float bvv = bias[colbase + wn * 64 + nf * 16 + cl];
#pragma unroll
                    for (int mf = 0; mf < 8; mf++)
#pragma unroll
                        for (int r = 0; r < 4; r++)
                            LDS[(mf * 16 + rb + r) * 264 + wn * 64 + nf * 16 + cl] =
                                f2bf(acc[mf][nf][r] + bvv);
                }
            }
            __syncthreads();
#pragma unroll
            for (int it = 0; it < 8; it++) {
                int row = (tid >> 5) + it * 16;
                int c8 = (tid & 31) * 8;
                uint2 lo = *(const uint2*)(LDS + row * 264 + c8);
                uint2 hi = *(const uint2*)(LDS + row * 264 + c8 + 4);
                uint4 val = make_uint4(lo.x, lo.y, hi.x, hi.y);
                u16* pp = dst + ((size_t)(bh0 + (c8 >> 7)) * L_ + lb + half * 128 + row) * HD_ + (c8 & 127);
                *(uint4*)pp = val;
            }
            __syncthreads();
        }
    } else {
        for (int half = 0; half < 2; half++) {
            if (wm == half) {
#pragma unroll
                for (int nf = 0; nf < 4; nf++) {
                    float bvv = bias[colbase + wn * 64 + nf * 16 + cl];
#pragma unroll
                    for (int mf = 0; mf < 8; mf++)
#pragma unroll
                        for (int r = 0; r < 4; r++)
                            LDS[(wn * 64 + nf * 16 + cl) * 136 + mf * 16 + rb + r] =
                                f2bf(acc[mf][nf][r] + bvv);
                }
            }
            __syncthreads();
#pragma unroll
            for (int it = 0; it < 8; it++) {
                int n = (tid >> 4) + it * 32;
                int c8 = (tid & 15) * 8;
                uint2 lo = *(const uint2*)(LDS + n * 136 + c8);
                uint2 hi = *(const uint2*)(LDS + n * 136 + c8 + 4);
                uint4 val = make_uint4(lo.x, lo.y, hi.x, hi.y);
                int cg = colbase + n;
                u16* pp = vT + ((size_t)(bi * NH_ + (cg >> 7)) * HD_ + (cg & 127)) * L_ + lb + half * 128 + c8;
                *(uint4*)pp = val;
            }
            __syncthreads();
        }
    }
}

// ---------------------------------------------------------------------------
// final projection, 256x256 8-phase: attn[8192,2048] @ Wo_t[2048,2048]^T + bo
// -> out fp32. 256 blocks = 1/CU, single round; direct fp32 stores.
// ---------------------------------------------------------------------------
__global__ __launch_bounds__(512, 2) void k_gemm_out(const u16* __restrict__ A, const u16* __restrict__ Wt,
                                                     const float* __restrict__ bo, float* __restrict__ out) {
    __shared__ u16 LDS[65536];
    const int lane = threadIdx.x & 63, wave = threadIdx.x >> 6;
    const int wm = wave >> 2, wn = wave & 3;

    const int xcd = blockIdx.x & 7, idx = blockIdx.x >> 3;
    const int nblk = idx >> 2;                 // 0..7
    const int mblk = xcd * 4 + (idx & 3);      // 0..31
    const int mb = mblk * 256, nb = nblk * 256;

    f32x4 acc[8][4];
    mainloop256(A + (size_t)mb * HS_, Wt + (size_t)nb * HS_, LDS, acc);

    const int rb = (lane >> 4) << 2, cl = lane & 15;
#pragma unroll
    for (int nf = 0; nf < 4; nf++) {
        int n = nb + wn * 64 + nf * 16 + cl;
        float bvv = bo[n];
#pragma unroll
        for (int mf = 0; mf < 8; mf++) {
            int m = mb + wm * 128 + mf * 16 + rb;
#pragma unroll
            for (int r = 0; r < 4; r++)
                out[(size_t)(m + r) * HS_ + n] = acc[mf][nf][r] + bvv;
        }
    }
}

// ---------------------------------------------------------------------------
// Fused feature map.
// TRANS=1 (k path): writes featT[bh][f][l] + per-block ksum partials.
//   kfT store is now COALESCED: y computed into registers (same order ->
//   bitwise-identical values/fsum), bounced through LDS (XOR-64 layout in H's
//   storage), then 8 consecutive lanes store one f-row's 128 B contiguously
//   (8 full-line segments per wave store vs 64 scattered 16 B before).
// TRANS=0 (q path): qf written back into H; inline 1/denom; fused attn
// numerator GEMM qf[64,256] @ kvT[bh][128,256]^T; direct attn stores.
// ---------------------------------------------------------------------------
template <int MASKED, int TRANS>
__global__ __launch_bounds__(256) void k_feat(const u16* __restrict__ X,
                                              const u16* __restrict__ W1t, const float* __restrict__ b1,
                                              const u16* __restrict__ W2t, const float* __restrict__ b2,
                                              const float* __restrict__ g, const float* __restrict__ be,
                                              const float* __restrict__ mask, const float* __restrict__ ksum,
                                              const u16* __restrict__ kvT,
                                              u16* __restrict__ feat, float* __restrict__ ksp,
                                              u16* __restrict__ attnOut) {
    __shared__ u16 As[64 * 32];
    __shared__ u16 Bs[256 * 32];
    __shared__ u16 H[64 * 264];
    __shared__ float MU[64], RS[64], FAC[64], RD[64];
    const int tid = threadIdx.x, lane = tid & 63, wave = tid >> 6;
    const int mb = blockIdx.x * 64;

    const int srow = lane >> 2, scol = (lane & 3) * 8;
    const int arow_rd = (lane & 15);
    const int kgrp = (lane >> 4) * 8;

    f32x4 acc[4][4];
    f32x4 zero = {0.f, 0.f, 0.f, 0.f};
#pragma unroll
    for (int i = 0; i < 4; i++)
#pragma unroll
        for (int j = 0; j < 4; j++) acc[i][j] = zero;

    // ---- GEMM1: x[64,128] @ W1t[256,128]^T ----
    for (int k0 = 0; k0 < 128; k0 += 32) {
        llds16(X + (size_t)(mb + wave * 16 + srow) * 128 + k0 + scol, As + wave * 512);
#pragma unroll
        for (int i = 0; i < 4; i++)
            llds16(W1t + (size_t)((wave * 4 + i) * 16 + srow) * 128 + k0 + scol,
                   Bs + (wave * 4 + i) * 512);
        __syncthreads();
        bf16x8 af[4], bg[4];
#pragma unroll
        for (int mt = 0; mt < 4; mt++) af[mt] = *(const bf16x8*)(As + (mt * 16 + arow_rd) * 32 + kgrp);
#pragma unroll
        for (int nt = 0; nt < 4; nt++) bg[nt] = *(const bf16x8*)(Bs + (wave * 64 + nt * 16 + arow_rd) * 32 + kgrp);
#pragma unroll
        for (int mt = 0; mt < 4; mt++)
#pragma unroll
            for (int nt = 0; nt < 4; nt++)
                acc[mt][nt] = __builtin_amdgcn_mfma_f32_16x16x32_bf16(af[mt], bg[nt], acc[mt][nt], 0, 0, 0);
        __syncthreads();
    }
    {
        const int rbase = (lane >> 4) << 2;
#pragma unroll
        for (int nt = 0; nt < 4; nt++) {
            int n = wave * 64 + nt * 16 + (lane & 15);
            float bvv = b1[n];
#pragma unroll
            for (int mt = 0; mt < 4; mt++)
#pragma unroll
                for (int r = 0; r < 4; r++) {
                    float v = fmaxf(acc[mt][nt][r] + bvv, 0.f);
                    H[(mt * 16 + rbase + r) * 264 + n] = f2bf(v);
                }
            acc[0][nt] = zero; acc[1][nt] = zero; acc[2][nt] = zero; acc[3][nt] = zero;
        }
    }
    __syncthreads();

    // ---- GEMM2: h1[64,256] @ W2t[256,256]^T ----
    for (int k0 = 0; k0 < 256; k0 += 32) {
#pragma unroll
        for (int i = 0; i < 4; i++)
            llds16(W2t + (size_t)((wave * 4 + i) * 16 + srow) * 256 + k0 + scol,
                   Bs + (wave * 4 + i) * 512);
        __syncthreads();
        bf16x8 af[4], bg[4];
#pragma unroll
        for (int mt = 0; mt < 4; mt++) af[mt] = *(const bf16x8*)(H + (mt * 16 + arow_rd) * 264 + k0 + kgrp);
#pragma unroll
        for (int nt = 0; nt < 4; nt++) bg[nt] = *(const bf16x8*)(Bs + (wave * 64 + nt * 16 + arow_rd) * 32 + kgrp);
#pragma unroll
        for (int mt = 0; mt < 4; mt++)
#pragma unroll
            for (int nt = 0; nt < 4; nt++)
                acc[mt][nt] = __builtin_amdgcn_mfma_f32_16x16x32_bf16(af[mt], bg[nt], acc[mt][nt], 0, 0, 0);
        __syncthreads();
    }
    {
        const int rbase = (lane >> 4) << 2;
#pragma unroll
        for (int nt = 0; nt < 4; nt++) {
            int n = wave * 64 + nt * 16 + (lane & 15);
            float bvv = b2[n];
#pragma unroll
            for (int mt = 0; mt < 4; mt++)
#pragma unroll
                for (int r = 0; r < 4; r++)
                    H[(mt * 16 + rbase + r) * 264 + n] = f2bf(acc[mt][nt][r] + bvv);
        }
    }
    __syncthreads();

    // ---- LayerNorm stats ----
    {
        for (int r = 0; r < 16; r++) {
            int row = wave * 16 + r;
            int j = lane * 4;
            uint2 u = *(const uint2*)(H + row * 264 + j);
            float x0 = bf2f((u16)(u.x & 0xffff)), x1 = bf2f((u16)(u.x >> 16));
            float x2 = bf2f((u16)(u.y & 0xffff)), x3 = bf2f((u16)(u.y >> 16));
            float s = x0 + x1 + x2 + x3;
            float ss = x0 * x0 + x1 * x1 + x2 * x2 + x3 * x3;
#pragma unroll
            for (int o = 32; o >= 1; o >>= 1) { s += __shfl_xor(s, o); ss += __shfl_xor(ss, o); }
            if (lane == 0) {
                float mu = s * (1.f / FD_);
                float var = ss * (1.f / FD_) - mu * mu;
                MU[row] = mu;
                RS[row] = rsqrtf(var + 1e-5f);
                float fac = 1.f;
                if (MASKED) {
                    int grow = mb + row;
                    int b = grow >> 16;
                    int l = grow & 4095;
                    fac = 1.f + mask[b * L_ + l];
                }
                FAC[row] = fac;
            }
        }
    }
    __syncthreads();

    if (!TRANS) {
        const int bh = mb >> 12;
        const u16* kvTb = kvT + (size_t)bh * HD_ * FD_;
        // LN -> qf bf16 written back into H; per-row 1/denom into RD
        {
            int j = lane * 4;
            float4 gg = *(const float4*)(g + j);
            float4 bb = *(const float4*)(be + j);
            float4 kk = *(const float4*)(ksum + (size_t)bh * FD_ + j);
            for (int r = 0; r < 16; r++) {
                int row = wave * 16 + r;
                float mu = MU[row], rstd = RS[row], fac = FAC[row];
                uint2 u = *(const uint2*)(H + row * 264 + j);
                float x0 = bf2f((u16)(u.x & 0xffff)), x1 = bf2f((u16)(u.x >> 16));
                float x2 = bf2f((u16)(u.y & 0xffff)), x3 = bf2f((u16)(u.y >> 16));
                u16 h0 = f2bf(((x0 - mu) * rstd * gg.x + bb.x) * fac);
                u16 h1 = f2bf(((x1 - mu) * rstd * gg.y + bb.y) * fac);
                u16 h2 = f2bf(((x2 - mu) * rstd * gg.z + bb.z) * fac);
                u16 h3 = f2bf(((x3 - mu) * rstd * gg.w + bb.w) * fac);
                uint2 o2;
                o2.x = (u32)h0 | ((u32)h1 << 16);
                o2.y = (u32)h2 | ((u32)h3 << 16);
                *(uint2*)(H + row * 264 + j) = o2;
                float dp = bf2f(h0) * kk.x + bf2f(h1) * kk.y + bf2f(h2) * kk.z + bf2f(h3) * kk.w;
#pragma unroll
                for (int o = 32; o >= 1; o >>= 1) dp += __shfl_xor(dp, o);
                if (lane == 0) RD[row] = 1.f / (dp + 1e-8f);
            }
        }
        __syncthreads();   // qf-H + RD visible
        // ---- GEMM3: qf[64,256] @ kvT[bh][128,256]^T -> attn rows ----
        f32x4 pacc[8];
#pragma unroll
        for (int i = 0; i < 8; i++) pacc[i] = zero;
        for (int k0 = 0; k0 < 256; k0 += 32) {
            // stage B slice [128 d][32 k] = 8KB; wave w stages rows [w*32, w*32+32)
            llds16(kvTb + (size_t)(wave * 32 + srow) * FD_ + k0 + scol, Bs + (wave * 32) * 32);
            llds16(kvTb + (size_t)(wave * 32 + 16 + srow) * FD_ + k0 + scol, Bs + (wave * 32 + 16) * 32);
            __syncthreads();
            bf16x8 af = *(const bf16x8*)(H + (wave * 16 + arow_rd) * 264 + k0 + kgrp);
#pragma unroll
            for (int nt = 0; nt < 8; nt++) {
                bf16x8 bg = *(const bf16x8*)(Bs + (nt * 16 + arow_rd) * 32 + kgrp);
                pacc[nt] = __builtin_amdgcn_mfma_f32_16x16x32_bf16(af, bg, pacc[nt], 0, 0, 0);
            }
            __syncthreads();
        }
        // divide + bounce via H rows [0..63][0..127], then coalesced stores
        const int rbase = (lane >> 4) << 2, cl = lane & 15;
#pragma unroll
        for (int nt = 0; nt < 8; nt++)
#pragma unroll
            for (int r = 0; r < 4; r++) {
                int row = wave * 16 + rbase + r;
                H[row * 264 + nt * 16 + cl] = f2bf(pacc[nt][r] * RD[row]);
            }
        __syncthreads();
        const int b = bh >> 4, h = bh & 15, lb = mb & 4095;
        const int c8 = (tid & 15) * 8;
#pragma unroll
        for (int it = 0; it < 4; it++) {
            int row = (tid >> 4) + it * 16;
            uint2 lo = *(const uint2*)(H + row * 264 + c8);
            uint2 hi = *(const uint2*)(H + row * 264 + c8 + 4);
            *(uint4*)(attnOut + ((size_t)(b * L_ + lb + row)) * HS_ + h * HD_ + c8) =
                make_uint4(lo.x, lo.y, hi.x, hi.y);
        }
    } else {
        // y into registers (same row order -> bitwise-identical fsum/values)
        const int f = tid;
        const int bh = mb >> 12, lb = mb & 4095;
        float gf = g[f], bf = be[f];
        float fsum = 0.f;
        uint4 pk[8];
#pragma unroll
        for (int lg = 0; lg < 8; lg++) {
            union { u16 h8[8]; uint4 v4; } pkk;
#pragma unroll
            for (int j = 0; j < 8; j++) {
                int row = lg * 8 + j;
                float x = bf2f(H[row * 264 + f]);
                float y = ((x - MU[row]) * RS[row] * gf + bf) * FAC[row];
                fsum += y;
                pkk.h8[j] = f2bf(y);
            }
            pk[lg] = pkk.v4;
        }
        ksp[((size_t)bh * 64 + (lb >> 6)) * FD_ + f] = fsum;
        __syncthreads();              // all H reads done; reuse H as bounce T
        // T layout (in H storage): uint4 chunk (f, c) at u16 idx f*64 + ((c^(f&7))*8)
        // 16B-aligned; XOR spreads banks (<=8-way aliasing on write & read).
#pragma unroll
        for (int c = 0; c < 8; c++)
            *(uint4*)(H + f * 64 + ((c ^ (f & 7)) * 8)) = pk[c];
        __syncthreads();
        // coalesced store: 8 consecutive lanes cover one f-row's 128 B
        const int cc = tid & 7;
#pragma unroll
        for (int i = 0; i < 8; i++) {
            int fr = (tid >> 3) + i * 32;
            uint4 v = *(const uint4*)(H + fr * 64 + ((cc ^ (fr & 7)) * 8));
            *(uint4*)(feat + ((size_t)bh * FD_ + fr) * L_ + lb + cc * 8) = v;
        }
    }
}

// reduce 64 per-block partials -> ksum[bh][f]
__global__ __launch_bounds__(256) void k_ksum2(const float* __restrict__ ksp, float* __restrict__ ksum) {
    const int bh = blockIdx.x, f = threadIdx.x;
    float s = 0.f;
    for (int i = 0; i < 64; i++) s += ksp[((size_t)bh * 64 + i) * FD_ + f];
    ksum[(size_t)bh * FD_ + f] = s;
}

// ---------------------------------------------------------------------------
// kv GEMM: per (f-block, k-slice, bh): kfT[256,4096] @ vT[128,4096]^T
// fp32 partials [ks*32+bh][f][d]; K split 4-way (256 blocks = 1 round)
// ---------------------------------------------------------------------------
__global__ __launch_bounds__(256) void k_gemm_kv(const u16* __restrict__ kfT, const u16* __restrict__ vT,
                                                 float* __restrict__ kvp) {
    __shared__ u16 As[4096], Bs[4096];
    f32x4 acc[4][4];
    const int mb = blockIdx.x * 128;    // f block (0..1)
    const int ks = blockIdx.y;          // k slice (0..3), 1024 each
    const int bh = blockIdx.z;
    gemm_mainloop(kfT + ((size_t)bh * FD_ + mb) * L_ + ks * 1024, L_,
                  vT + (size_t)bh * HD_ * L_ + ks * 1024, L_, 1024, As, Bs, acc);
    const int lane = threadIdx.x & 63, wave = threadIdx.x >> 6;
    const int wm = wave >> 1, wn = wave & 1;
    const int n0 = wn * 64 + (lane & 15);
    const int m0 = mb + wm * 64 + ((lane >> 4) << 2);
    float* o = kvp + (size_t)(ks * 32 + bh) * (FD_ * HD_);
#pragma unroll
    for (int nt = 0; nt < 4; nt++)
#pragma unroll
        for (int mt = 0; mt < 4; mt++)
#pragma unroll
            for (int r = 0; r < 4; r++)
                o[(size_t)(m0 + mt * 16 + r) * HD_ + n0 + nt * 16] = acc[mt][nt][r];
}

// reduce 4 k-slice partials -> kvT[bh][d][f] bf16
__global__ __launch_bounds__(256) void k_kvred(const float* __restrict__ kvp, u16* __restrict__ kvT) {
    const int p = blockIdx.x, bh = blockIdx.y, t = threadIdx.x;
    const int e0 = p * 4096 + t * 16;
    float s[16];
#pragma unroll
    for (int i = 0; i < 16; i++) s[i] = 0.f;
    for (int c = 0; c < 4; c++) {
        const float* src = kvp + ((size_t)(c * 32 + bh)) * 32768 + e0;
#pragma unroll
        for (int i = 0; i < 16; i += 4) {
            float4 vv = *(const float4*)(src + i);
            s[i] += vv.x; s[i + 1] += vv.y; s[i + 2] += vv.z; s[i + 3] += vv.w;
        }
    }
#pragma unroll
    for (int i = 0; i < 16; i++) {
        int e = e0 + i, fq = e >> 7, d = e & 127;
        kvT[((size_t)bh * HD_ + d) * FD_ + fq] = f2bf(s[i]);
    }
}

// ---------------------------------------------------------------------------
// workspace layout (bytes), total ~237 MiB.  Launch order:
//   cvt -> transpose -> qkv -> feat<k> -> ksum2 -> gemm_kv -> kvred
//   -> feat<q>(attn fused) -> out
//   [0]          Wqkv_t 25,165,824 then Xbf 33,554,432 (dead after qkv)
//   [67108864]   kfT   67,108,864   ([bh][f][l])
//   [134217728]  qbuf  33,554,432   (live until feat<q>)
//   [167772160]  kbuf  33,554,432   -> kvp (16.8MB fp32, after feat<k>)
//                                   -> attn (after kvred consumes kvp)
//   [201326592]  vT    33,554,432   ([bh][d][l])
//   [234881024]  Wo_t   8,388,608
//   [243269632]  Wf1_t     65,536
//   [243335168]  Wf2_t    131,072
//   [243466240]  ksp    2,097,152
//   [245563392]  kvT    2,097,152
//   [247660544]  ksum      32,768   -> end 247,693,312
// ---------------------------------------------------------------------------
extern "C" void kernel_launch(void* const* d_in, const int* in_sizes, int n_in,
                              void* d_out, int out_size, void* d_ws, size_t ws_size,
                              hipStream_t stream) {
    const float* hs  = (const float*)d_in[0];
    const float* msk = (const float*)d_in[1];
    const float* Wq  = (const float*)d_in[2];  const float* bq  = (const float*)d_in[3];
    const float* Wk  = (const float*)d_in[4];  const float* bk  = (const float*)d_in[5];
    const float* Wv  = (const float*)d_in[6];  const float* bv  = (const float*)d_in[7];
    const float* Wo  = (const float*)d_in[8];  const float* bo  = (const float*)d_in[9];
    const float* Wf1 = (const float*)d_in[10]; const float* bf1 = (const float*)d_in[11];
    const float* Wf2 = (const float*)d_in[12]; const float* bf2 = (const float*)d_in[13];
    const float* lng = (const float*)d_in[14]; const float* lnb = (const float*)d_in[15];
    float* out = (float*)d_out;
    char* w = (char*)d_ws;

    u16* Wqkv_t = (u16*)(w + 0);               // dead after qkv
    u16* Xbf    = (u16*)(w + 25165824u);       // dead after qkv
    u16* kfT    = (u16*)(w + 67108864u);
    u16* qbuf   = (u16*)(w + 134217728u);
    u16* kbuf   = (u16*)(w + 167772160u);
    float* kvp  = (float*)(w + 167772160u);    // alias: kbuf dead after feat<k>
    u16* attn   = (u16*)(w + 167772160u);      // alias: kvp dead after kvred
    u16* vT     = (u16*)(w + 201326592u);
    u16* Wo_t   = (u16*)(w + 234881024u);
    u16* Wf1_t  = (u16*)(w + 243269632u);
    u16* Wf2_t  = (u16*)(w + 243335168u);
    float* ksp  = (float*)(w + 243466240u);
    u16* kvT    = (u16*)(w + 245563392u);
    float* ksum = (float*)(w + 247660544u);

    k_cvt<<<dim3(8192), 256, 0, stream>>>(hs, Xbf);
    k_transpose<<<dim3(64, 64, 6), dim3(32, 8), 0, stream>>>(Wq, Wk, Wv, Wo, Wf1, Wf2,
                                                             Wqkv_t, Wo_t, Wf1_t, Wf2_t);
    k_gemm_qkv<<<dim3(768), 512, 0, stream>>>(Xbf, Wqkv_t, bq, bk, bv, qbuf, kbuf, vT);
    // k-chain first so ksum + kvT are ready before feat<q> (attn fused there)
    k_feat<1, 1><<<dim3(2048), 256, 0, stream>>>(kbuf, Wf1_t, bf1, Wf2_t, bf2, lng, lnb, msk,
                                                 nullptr, nullptr, kfT, ksp, nullptr);
    k_ksum2<<<dim3(32), 256, 0, stream>>>(ksp, ksum);
    k_gemm_kv<<<dim3(2, 4, 32), 256, 0, stream>>>(kfT, vT, kvp);
    k_kvred<<<dim3(8, 32), 256, 0, stream>>>(kvp, kvT);
    k_feat<0, 0><<<dim3(2048), 256, 0, stream>>>(qbuf, Wf1_t, bf1, Wf2_t, bf2, lng, lnb, msk,
                                                 ksum, kvT, nullptr, nullptr, attn);
    k_gemm_out<<<dim3(256), 512, 0, stream>>>(attn, Wo_t, bo, out);
}

// Round 7
// 671.328 us; speedup vs baseline: 1.0302x; 1.0302x over previous
//
#include <hip/hip_runtime.h>

typedef unsigned short u16;
typedef unsigned int u32;
typedef __attribute__((ext_vector_type(8))) short bf16x8;
typedef __attribute__((ext_vector_type(4))) float f32x4;

#define B_ 2
#define L_ 4096
#define HS_ 2048
#define NH_ 16
#define HD_ 128
#define FD_ 256

__device__ __forceinline__ float bf2f(u16 u) { return __uint_as_float(((u32)u) << 16); }
__device__ __forceinline__ u16 f2bf(float f) {
    u32 x = __float_as_uint(f);
    return (u16)((x + 0x7fffu + ((x >> 16) & 1u)) >> 16);
}

// async global->LDS, 16B per lane; LDS dest = wave-uniform base + lane*16
__device__ __forceinline__ void llds16(const u16* g, u16* l) {
    __builtin_amdgcn_global_load_lds((const __attribute__((address_space(1))) void*)g,
                                     (__attribute__((address_space(3))) void*)l, 16, 0, 0);
}

// ---------------------------------------------------------------------------
// Shared MFMA mainloop: C[128x128] block, 4 waves (2x2), 16x16x32 bf16 MFMA.
// A: [M,K] row-major bf16. Bt: [N,K] row-major bf16. LDS tiles [128][32].
// A-frag: A[m=lane&15][k=(lane>>4)*8+j]; D-frag: D[m=(lane>>4)*4+r][n=lane&15]
// (used by the kv gemm)
// ---------------------------------------------------------------------------
__device__ __forceinline__ void gemm_mainloop(const u16* __restrict__ Ab, int lda,
                                              const u16* __restrict__ Bb, int ldb,
                                              int K, u16* As, u16* Bs, f32x4 (&acc)[4][4]) {
    const int tid  = threadIdx.x;
    const int lane = tid & 63;
    const int wave = tid >> 6;
    const int wm = wave >> 1, wn = wave & 1;

    f32x4 zero = {0.f, 0.f, 0.f, 0.f};
#pragma unroll
    for (int i = 0; i < 4; i++)
#pragma unroll
        for (int j = 0; j < 4; j++) acc[i][j] = zero;

    const int srow = lane >> 2;
    const int scol = (lane & 3) * 8;
    const u16* pa = Ab + (size_t)(wave * 32 + srow) * lda + scol;
    const u16* pb = Bb + (size_t)(wave * 32 + srow) * ldb + scol;
    u16* la = As + wave * 1024;
    u16* lb = Bs + wave * 1024;

    const int arow = (wm * 64 + (lane & 15)) * 32 + (lane >> 4) * 8;
    const int brow = (wn * 64 + (lane & 15)) * 32 + (lane >> 4) * 8;

    for (int k0 = 0; k0 < K; k0 += 32) {
        llds16(pa, la);
        llds16(pa + 16 * lda, la + 512);
        llds16(pb, lb);
        llds16(pb + 16 * ldb, lb + 512);
        pa += 32; pb += 32;
        __syncthreads();
        bf16x8 af[4], bg[4];
#pragma unroll
        for (int mt = 0; mt < 4; mt++) af[mt] = *(const bf16x8*)(As + arow + mt * 512);
#pragma unroll
        for (int nt = 0; nt < 4; nt++) bg[nt] = *(const bf16x8*)(Bs + brow + nt * 512);
#pragma unroll
        for (int mt = 0; mt < 4; mt++)
#pragma unroll
            for (int nt = 0; nt < 4; nt++)
                acc[mt][nt] = __builtin_amdgcn_mfma_f32_16x16x32_bf16(af[mt], bg[nt], acc[mt][nt], 0, 0, 0);
        __syncthreads();
    }
}

// ---------------------------------------------------------------------------
// fp32 -> bf16 bulk convert (hidden_states -> Xbf). n multiple of 2048.
// ---------------------------------------------------------------------------
__global__ __launch_bounds__(256) void k_cvt(const float* __restrict__ src, u16* __restrict__ dst) {
    size_t i = ((size_t)blockIdx.x * 256 + threadIdx.x) * 8;
    float4 a = *(const float4*)(src + i);
    float4 b = *(const float4*)(src + i + 4);
    union { u16 h[8]; uint4 v; } o;
    o.h[0] = f2bf(a.x); o.h[1] = f2bf(a.y); o.h[2] = f2bf(a.z); o.h[3] = f2bf(a.w);
    o.h[4] = f2bf(b.x); o.h[5] = f2bf(b.y); o.h[6] = f2bf(b.z); o.h[7] = f2bf(b.w);
    *(uint4*)(dst + i) = o.v;
}

// ---------------------------------------------------------------------------
// Weight transposes + fp32->bf16: W[k][n] fp32 -> Wt[n][k] bf16
// ---------------------------------------------------------------------------
__global__ __launch_bounds__(256) void k_transpose(const float* Wq, const float* Wk, const float* Wv,
                                                   const float* Wo, const float* Wf1, const float* Wf2,
                                                   u16* Wqkv_t, u16* Wo_t, u16* Wf1_t, u16* Wf2_t) {
    const float* src; u16* dst; int R, C;
    switch (blockIdx.z) {
        case 0: src = Wq;  dst = Wqkv_t;                R = 2048; C = 2048; break;
        case 1: src = Wk;  dst = Wqkv_t + 2048 * 2048;  R = 2048; C = 2048; break;
        case 2: src = Wv;  dst = Wqkv_t + 2 * 2048 * 2048; R = 2048; C = 2048; break;
        case 3: src = Wo;  dst = Wo_t;                  R = 2048; C = 2048; break;
        case 4: src = Wf1; dst = Wf1_t;                 R = 128;  C = 256;  break;
        default: src = Wf2; dst = Wf2_t;                R = 256;  C = 256;  break;
    }
    int c0 = blockIdx.x * 32, r0 = blockIdx.y * 32;
    if (c0 >= C || r0 >= R) return;
    __shared__ u16 tile[32][33];
    int tx = threadIdx.x, ty = threadIdx.y;
    for (int i = ty; i < 32; i += 8) tile[i][tx] = f2bf(src[(size_t)(r0 + i) * C + c0 + tx]);
    __syncthreads();
    for (int i = ty; i < 32; i += 8) dst[(size_t)(c0 + i) * R + r0 + tx] = tile[tx][i];
}

// ---------------------------------------------------------------------------
// 256x256 8-phase mainloop template (T1+T2+T3+T4+T5), K=2048, stride 2048.
// (unchanged — see round-1 comments for the schedule derivation)
// ---------------------------------------------------------------------------
#define QKV_BAR() { __builtin_amdgcn_sched_barrier(0); __builtin_amdgcn_s_barrier(); \
                    __builtin_amdgcn_sched_barrier(0); }
#define QKV_LGKM0() { asm volatile("s_waitcnt lgkmcnt(0)" ::: "memory"); \
                      __builtin_amdgcn_sched_barrier(0); }

__device__ __forceinline__ void mainloop256(const u16* __restrict__ Abase,
                                            const u16* __restrict__ Bbase,
                                            u16* LDS, f32x4 (&acc)[8][4]) {
    const int tid = threadIdx.x, lane = tid & 63, wave = tid >> 6;
    const int wm = wave >> 2, wn = wave & 3;

    // staging source coords (inverse st_16x32 swizzle). Half-tile = 128x64 bf16
    // = 16 subtiles of [16 rows][32 cols] (1024B). j=0 -> subtiles 0-7, j=1 -> 8-15.
    int r0g, c0g, r1g, c1g;
    { int p = tid * 16; int s = p >> 10, q = p & 1023; q ^= ((q >> 9) & 1) << 5;
      r0g = (s >> 1) * 16 + (q >> 6); c0g = (s & 1) * 32 + ((q & 63) >> 1); }
    { int p = 8192 + tid * 16; int s = p >> 10, q = p & 1023; q ^= ((q >> 9) & 1) << 5;
      r1g = (s >> 1) * 16 + (q >> 6); c1g = (s & 1) * 32 + ((q & 63) >> 1); }
    const int voff0 = r0g * HS_ + c0g;
    const int voff1 = r1g * HS_ + c1g;

    // read-side swizzled in-subtile offset (u16 units): row=lane&15, 16B chunk=(lane>>4)
    int qby = (lane & 15) * 64 + (lane >> 4) * 16;
    qby ^= ((qby >> 9) & 1) << 5;
    const int qh = qby >> 1;

#define STG(G, soff, dstu) { \
    llds16((G) + (soff) + voff0, LDS + (dstu) + wave * 512); \
    llds16((G) + (soff) + voff1, LDS + (dstu) + 4096 + wave * 512); }

    const size_t a0 = 0, a1 = (size_t)128 * HS_;
    const size_t b0 = 0, b1 = (size_t)128 * HS_;

    // prologue: tile0 {B0,B1,A0,A1} + tile1 {B0,B1,A0}; A1(1) staged at t=0 P1.
    STG(Bbase, b0, 32768); STG(Bbase, b1, 40960);
    STG(Abase, a0, 0);     STG(Abase, a1, 8192);
    STG(Bbase, b0 + 64, 49152); STG(Bbase, b1 + 64, 57344);
    STG(Abase, a0 + 64, 16384);
    asm volatile("s_waitcnt vmcnt(6)" ::: "memory");   // tile0 complete
    QKV_BAR();

    f32x4 zero = {0.f, 0.f, 0.f, 0.f};
#pragma unroll
    for (int i = 0; i < 8; i++)
#pragma unroll
        for (int j = 0; j < 4; j++) acc[i][j] = zero;

    const int NT = HS_ / 64;   // 32
    bf16x8 afr[4][2], bfr[4][2];
    for (int t = 0; t < NT; t++) {
        const int bsel = t & 1;
        const u16* Ah = LDS + bsel * 16384 + wm * 8192;
        const u16* Bh = LDS + 32768 + bsel * 16384 + (wn >> 1) * 8192;
        const int bg0 = (wn & 1) * 4;
        const size_t kc1 = (size_t)(t + 1) * 64, kc2 = (size_t)(t + 2) * 64;

        // ---- phase 1 ----
#pragma unroll
        for (int mf = 0; mf < 4; mf++)
#pragma unroll
            for (int ks = 0; ks < 2; ks++)
                afr[mf][ks] = *(const bf16x8*)(Ah + (mf * 2 + ks) * 512 + qh);
#pragma unroll
        for (int nf = 0; nf < 4; nf++)
#pragma unroll
            for (int ks = 0; ks < 2; ks++)
                bfr[nf][ks] = *(const bf16x8*)(Bh + ((bg0 + nf) * 2 + ks) * 512 + qh);
        if (t + 1 < NT) STG(Abase, a1 + kc1, (bsel ^ 1) * 16384 + 8192);    // A1(t+1)
        QKV_BAR();
        QKV_LGKM0();
        __builtin_amdgcn_s_setprio(1);
#pragma unroll
        for (int mf = 0; mf < 4; mf++)
#pragma unroll
            for (int nf = 0; nf < 2; nf++)
#pragma unroll
                for (int ks = 0; ks < 2; ks++)
                    acc[mf][nf] = __builtin_amdgcn_mfma_f32_16x16x32_bf16(afr[mf][ks], bfr[nf][ks], acc[mf][nf], 0, 0, 0);
        __builtin_amdgcn_s_setprio(0);
        QKV_BAR();
        // ---- phase 2 ----
        if (t + 2 < NT) STG(Bbase, b0 + kc2, 32768 + bsel * 16384);        // B0(t+2)
        QKV_BAR();
        __builtin_amdgcn_s_setprio(1);
#pragma unroll
        for (int mf = 0; mf < 4; mf++)
#pragma unroll
            for (int nf = 2; nf < 4; nf++)
#pragma unroll
                for (int ks = 0; ks < 2; ks++)
                    acc[mf][nf] = __builtin_amdgcn_mfma_f32_16x16x32_bf16(afr[mf][ks], bfr[nf][ks], acc[mf][nf], 0, 0, 0);
        __builtin_amdgcn_s_setprio(0);
        QKV_BAR();
        // ---- phase 3 ----
#pragma unroll
        for (int mf = 0; mf < 4; mf++)
#pragma unroll
            for (int ks = 0; ks < 2; ks++)
                afr[mf][ks] = *(const bf16x8*)(Ah + ((mf + 4) * 2 + ks) * 512 + qh);
        if (t + 2 < NT) STG(Bbase, b1 + kc2, 32768 + bsel * 16384 + 8192); // B1(t+2)
        QKV_BAR();
        QKV_LGKM0();
        __builtin_amdgcn_s_setprio(1);
#pragma unroll
        for (int mf = 0; mf < 4; mf++)
#pragma unroll
            for (int nf = 0; nf < 2; nf++)
#pragma unroll
                for (int ks = 0; ks < 2; ks++)
                    acc[mf + 4][nf] = __builtin_amdgcn_mfma_f32_16x16x32_bf16(afr[mf][ks], bfr[nf][ks], acc[mf + 4][nf], 0, 0, 0);
        __builtin_amdgcn_s_setprio(0);
        QKV_BAR();
        // ---- phase 4 ----
        if (t + 2 < NT) STG(Abase, a0 + kc2, bsel * 16384);                 // A0(t+2)
        QKV_BAR();
        __builtin_amdgcn_s_setprio(1);
#pragma unroll
        for (int mf = 0; mf < 4; mf++)
#pragma unroll
            for (int nf = 2; nf < 4; nf++)
#pragma unroll
                for (int ks = 0; ks < 2; ks++)
                    acc[mf + 4][nf] = __builtin_amdgcn_mfma_f32_16x16x32_bf16(afr[mf][ks], bfr[nf][ks], acc[mf + 4][nf], 0, 0, 0);
        __builtin_amdgcn_s_setprio(0);
        if (t + 2 < NT) { asm volatile("s_waitcnt vmcnt(6)" ::: "memory"); }
        else if (t + 1 < NT) { asm volatile("s_waitcnt vmcnt(0)" ::: "memory"); }
        QKV_BAR();
    }
#undef STG
}

// ---------------------------------------------------------------------------
// QKV gemm: Xbf[8192,2048] @ Wqkv_t[6144,2048]^T + bias ->
//   q,k:[bh][l][d], vT:[bh][d][l].
// XCD mapping: all 32 concurrent blocks of an XCD share ONE B n-panel
// (nblk = xcd*3 + round, mblk = r&31; bijective 8x3x32=768) -> B stages hit
// XCD L2 after warmup; X streams via L3. Cuts vmcnt(6) stall latency.
// ---------------------------------------------------------------------------
__global__ __launch_bounds__(512, 2) void k_gemm_qkv(
        const u16* __restrict__ X, const u16* __restrict__ Wt,
        const float* __restrict__ bq, const float* __restrict__ bk, const float* __restrict__ bv,
        u16* __restrict__ qout, u16* __restrict__ kout, u16* __restrict__ vT) {
    __shared__ u16 LDS[65536];                 // 128 KB: A bufs [0,32768), B bufs [32768,65536)
    const int tid = threadIdx.x, lane = tid & 63, wave = tid >> 6;
    const int wm = wave >> 2, wn = wave & 3;

    // n-shared XCD chunking: 768 blocks = 8 XCDs x (3 n-rounds x 32 m)
    const int xcd = blockIdx.x & 7, r = blockIdx.x >> 3;   // r in [0,96)
    const int nblk = xcd * 3 + (r >> 5);       // 0..23
    const int mblk = r & 31;                   // 0..31
    const int mb = mblk * 256, nb = nblk * 256;

    f32x4 acc[8][4];
    mainloop256(X + (size_t)mb * HS_, Wt + (size_t)nb * HS_, LDS, acc);

    // ---- epilogue: LDS-bounce, 2 half-passes (rows 0-127 / 128-255) ----
    const int which = nblk >> 3;                 // 0=q,1=k,2=v
    const int colbase = (nblk & 7) * 256;        // column within the 2048-wide output
    const int bi = mb >> 12, lb = mb & 4095;
    const float* bias = (which == 0) ? bq : (which == 1 ? bk : bv);
    const int rb = (lane >> 4) << 2, cl = lane & 15;

    if (which < 2) {
        u16* dst = (which == 0) ? qout : kout;
        const int bh0 = bi * NH_ + (colbase >> 7);
        for (int half = 0; half < 2; half++) {
            if (wm == half) {
#pragma unroll
                for (int nf = 0; nf < 4; nf++) {
                    float bvv = bias[colbase + wn * 64 + nf * 16 + cl];
#pragma unroll
                    for (int mf = 0; mf < 8; mf++)
#pragma unroll
                        for (int r2 = 0; r2 < 4; r2++)
                            LDS[(mf * 16 + rb + r2) * 264 + wn * 64 + nf * 16 + cl] =
                                f2bf(acc[mf][nf][r2] + bvv);
                }
            }
            __syncthreads();
#pragma unroll
            for (int it = 0; it < 8; it++) {
                int row = (tid >> 5) + it * 16;
                int c8 = (tid & 31) * 8;
                uint2 lo = *(const uint2*)(LDS + row * 264 + c8);
                uint2 hi = *(const uint2*)(LDS + row * 264 + c8 + 4);
                uint4 val = make_uint4(lo.x, lo.y, hi.x, hi.y);
                u16* pp = dst + ((size_t)(bh0 + (c8 >> 7)) * L_ + lb + half * 128 + row) * HD_ + (c8 & 127);
                *(uint4*)pp = val;
            }
            __syncthreads();
        }
    } else {
        for (int half = 0; half < 2; half++) {
            if (wm == half) {
#pragma unroll
                for (int nf = 0; nf < 4; nf++) {
                    float bvv = bias[colbase + wn * 64 + nf * 16 + cl];
#pragma unroll
                    for (int mf = 0; mf < 8; mf++)
#pragma unroll
                        for (int r2 = 0; r2 < 4; r2++)
                            LDS[(wn * 64 + nf * 16 + cl) * 136 + mf * 16 + rb + r2] =
                                f2bf(acc[mf][nf][r2] + bvv);
                }
            }
            __syncthreads();
#pragma unroll
            for (int it = 0; it < 8; it++) {
                int n = (tid >> 4) + it * 32;
                int c8 = (tid & 15) * 8;
                uint2 lo = *(const uint2*)(LDS + n * 136 + c8);
                uint2 hi = *(const uint2*)(LDS + n * 136 + c8 + 4);
                uint4 val = make_uint4(lo.x, lo.y, hi.x, hi.y);
                int cg = colbase + n;
                u16* pp = vT + ((size_t)(bi * NH_ + (cg >> 7)) * HD_ + (cg & 127)) * L_ + lb + half * 128 + c8;
                *(uint4*)pp = val;
            }
            __syncthreads();
        }
    }
}

// ---------------------------------------------------------------------------
// final projection, 256x256 8-phase: attn[8192,2048] @ Wo_t[2048,2048]^T + bo
// -> out fp32. 256 blocks = 1/CU, single round; direct fp32 stores.
// XCD mapping: nblk = xcd (each XCD owns its 1MB Wo panel, L2-resident).
// ---------------------------------------------------------------------------
__global__ __launch_bounds__(512, 2) void k_gemm_out(const u16* __restrict__ A, const u16* __restrict__ Wt,
                                                     const float* __restrict__ bo, float* __restrict__ out) {
    __shared__ u16 LDS[65536];
    const int lane = threadIdx.x & 63, wave = threadIdx.x >> 6;
    const int wm = wave >> 2, wn = wave & 3;

    const int xcd = blockIdx.x & 7, idx = blockIdx.x >> 3;
    const int nblk = xcd;                      // 0..7
    const int mblk = idx;                      // 0..31
    const int mb = mblk * 256, nb = nblk * 256;

    f32x4 acc[8][4];
    mainloop256(A + (size_t)mb * HS_, Wt + (size_t)nb * HS_, LDS, acc);

    const int rb = (lane >> 4) << 2, cl = lane & 15;
#pragma unroll
    for (int nf = 0; nf < 4; nf++) {
        int n = nb + wn * 64 + nf * 16 + cl;
        float bvv = bo[n];
#pragma unroll
        for (int mf = 0; mf < 8; mf++) {
            int m = mb + wm * 128 + mf * 16 + rb;
#pragma unroll
            for (int r = 0; r < 4; r++)
                out[(size_t)(m + r) * HS_ + n] = acc[mf][nf][r] + bvv;
        }
    }
}

// ---------------------------------------------------------------------------
// Fused feature map.
// TRANS=1 (k path): writes featT[bh][f][l] + per-block ksum partials.
// TRANS=0 (q path): qf written back into H; inline 1/denom; fused attn
// numerator GEMM qf[64,256] @ kvT[bh][128,256]^T; direct attn stores.
// ---------------------------------------------------------------------------
template <int MASKED, int TRANS>
__global__ __launch_bounds__(256) void k_feat(const u16* __restrict__ X,
                                              const u16* __restrict__ W1t, const float* __restrict__ b1,
                                              const u16* __restrict__ W2t, const float* __restrict__ b2,
                                              const float* __restrict__ g, const float* __restrict__ be,
                                              const float* __restrict__ mask, const float* __restrict__ ksum,
                                              const u16* __restrict__ kvT,
                                              u16* __restrict__ feat, float* __restrict__ ksp,
                                              u16* __restrict__ attnOut) {
    __shared__ u16 As[64 * 32];
    __shared__ u16 Bs[256 * 32];
    __shared__ u16 H[64 * 264];
    __shared__ float MU[64], RS[64], FAC[64], RD[64];
    const int tid = threadIdx.x, lane = tid & 63, wave = tid >> 6;
    const int mb = blockIdx.x * 64;

    const int srow = lane >> 2, scol = (lane & 3) * 8;
    const int arow_rd = (lane & 15);
    const int kgrp = (lane >> 4) * 8;

    f32x4 acc[4][4];
    f32x4 zero = {0.f, 0.f, 0.f, 0.f};
#pragma unroll
    for (int i = 0; i < 4; i++)
#pragma unroll
        for (int j = 0; j < 4; j++) acc[i][j] = zero;

    // ---- GEMM1: x[64,128] @ W1t[256,128]^T ----
    for (int k0 = 0; k0 < 128; k0 += 32) {
        llds16(X + (size_t)(mb + wave * 16 + srow) * 128 + k0 + scol, As + wave * 512);
#pragma unroll
        for (int i = 0; i < 4; i++)
            llds16(W1t + (size_t)((wave * 4 + i) * 16 + srow) * 128 + k0 + scol,
                   Bs + (wave * 4 + i) * 512);
        __syncthreads();
        bf16x8 af[4], bg[4];
#pragma unroll
        for (int mt = 0; mt < 4; mt++) af[mt] = *(const bf16x8*)(As + (mt * 16 + arow_rd) * 32 + kgrp);
#pragma unroll
        for (int nt = 0; nt < 4; nt++) bg[nt] = *(const bf16x8*)(Bs + (wave * 64 + nt * 16 + arow_rd) * 32 + kgrp);
#pragma unroll
        for (int mt = 0; mt < 4; mt++)
#pragma unroll
            for (int nt = 0; nt < 4; nt++)
                acc[mt][nt] = __builtin_amdgcn_mfma_f32_16x16x32_bf16(af[mt], bg[nt], acc[mt][nt], 0, 0, 0);
        __syncthreads();
    }
    {
        const int rbase = (lane >> 4) << 2;
#pragma unroll
        for (int nt = 0; nt < 4; nt++) {
            int n = wave * 64 + nt * 16 + (lane & 15);
            float bvv = b1[n];
#pragma unroll
            for (int mt = 0; mt < 4; mt++)
#pragma unroll
                for (int r = 0; r < 4; r++) {
                    float v = fmaxf(acc[mt][nt][r] + bvv, 0.f);
                    H[(mt * 16 + rbase + r) * 264 + n] = f2bf(v);
                }
            acc[0][nt] = zero; acc[1][nt] = zero; acc[2][nt] = zero; acc[3][nt] = zero;
        }
    }
    __syncthreads();

    // ---- GEMM2: h1[64,256] @ W2t[256,256]^T ----
    for (int k0 = 0; k0 < 256; k0 += 32) {
#pragma unroll
        for (int i = 0; i < 4; i++)
            llds16(W2t + (size_t)((wave * 4 + i) * 16 + srow) * 256 + k0 + scol,
                   Bs + (wave * 4 + i) * 512);
        __syncthreads();
        bf16x8 af[4], bg[4];
#pragma unroll
        for (int mt = 0; mt < 4; mt++) af[mt] = *(const bf16x8*)(H + (mt * 16 + arow_rd) * 264 + k0 + kgrp);
#pragma unroll
        for (int nt = 0; nt < 4; nt++) bg[nt] = *(const bf16x8*)(Bs + (wave * 64 + nt * 16 + arow_rd) * 32 + kgrp);
#pragma unroll
        for (int mt = 0; mt < 4; mt++)
#pragma unroll
            for (int nt = 0; nt < 4; nt++)
                acc[mt][nt] = __builtin_amdgcn_mfma_f32_16x16x32_bf16(af[mt], bg[nt], acc[mt][nt], 0, 0, 0);
        __syncthreads();
    }
    {
        const int rbase = (lane >> 4) << 2;
#pragma unroll
        for (int nt = 0; nt < 4; nt++) {
            int n = wave * 64 + nt * 16 + (lane & 15);
            float bvv = b2[n];
#pragma unroll
            for (int mt = 0; mt < 4; mt++)
#pragma unroll
                for (int r = 0; r < 4; r++)
                    H[(mt * 16 + rbase + r) * 264 + n] = f2bf(acc[mt][nt][r] + bvv);
        }
    }
    __syncthreads();

    // ---- LayerNorm stats ----
    {
        for (int r = 0; r < 16; r++) {
            int row = wave * 16 + r;
            int j = lane * 4;
            uint2 u = *(const uint2*)(H + row * 264 + j);
            float x0 = bf2f((u16)(u.x & 0xffff)), x1 = bf2f((u16)(u.x >> 16));
            float x2 = bf2f((u16)(u.y & 0xffff)), x3 = bf2f((u16)(u.y >> 16));
            float s = x0 + x1 + x2 + x3;
            float ss = x0 * x0 + x1 * x1 + x2 * x2 + x3 * x3;
#pragma unroll
            for (int o = 32; o >= 1; o >>= 1) { s += __shfl_xor(s, o); ss += __shfl_xor(ss, o); }
            if (lane == 0) {
                float mu = s * (1.f / FD_);
                float var = ss * (1.f / FD_) - mu * mu;
                MU[row] = mu;
                RS[row] = rsqrtf(var + 1e-5f);
                float fac = 1.f;
                if (MASKED) {
                    int grow = mb + row;
                    int b = grow >> 16;
                    int l = grow & 4095;
                    fac = 1.f + mask[b * L_ + l];
                }
                FAC[row] = fac;
            }
        }
    }
    __syncthreads();

    if (!TRANS) {
        const int bh = mb >> 12;
        const u16* kvTb = kvT + (size_t)bh * HD_ * FD_;
        // LN -> qf bf16 written back into H; per-row 1/denom into RD
        {
            int j = lane * 4;
            float4 gg = *(const float4*)(g + j);
            float4 bb = *(const float4*)(be + j);
            float4 kk = *(const float4*)(ksum + (size_t)bh * FD_ + j);
            for (int r = 0; r < 16; r++) {
                int row = wave * 16 + r;
                float mu = MU[row], rstd = RS[row], fac = FAC[row];
                uint2 u = *(const uint2*)(H + row * 264 + j);
                float x0 = bf2f((u16)(u.x & 0xffff)), x1 = bf2f((u16)(u.x >> 16));
                float x2 = bf2f((u16)(u.y & 0xffff)), x3 = bf2f((u16)(u.y >> 16));
                u16 h0 = f2bf(((x0 - mu) * rstd * gg.x + bb.x) * fac);
                u16 h1 = f2bf(((x1 - mu) * rstd * gg.y + bb.y) * fac);
                u16 h2 = f2bf(((x2 - mu) * rstd * gg.z + bb.z) * fac);
                u16 h3 = f2bf(((x3 - mu) * rstd * gg.w + bb.w) * fac);
                uint2 o2;
                o2.x = (u32)h0 | ((u32)h1 << 16);
                o2.y = (u32)h2 | ((u32)h3 << 16);
                *(uint2*)(H + row * 264 + j) = o2;
                float dp = bf2f(h0) * kk.x + bf2f(h1) * kk.y + bf2f(h2) * kk.z + bf2f(h3) * kk.w;
#pragma unroll
                for (int o = 32; o >= 1; o >>= 1) dp += __shfl_xor(dp, o);
                if (lane == 0) RD[row] = 1.f / (dp + 1e-8f);
            }
        }
        __syncthreads();   // qf-H + RD visible
        // ---- GEMM3: qf[64,256] @ kvT[bh][128,256]^T -> attn rows ----
        f32x4 pacc[8];
#pragma unroll
        for (int i = 0; i < 8; i++) pacc[i] = zero;
        for (int k0 = 0; k0 < 256; k0 += 32) {
            // stage B slice [128 d][32 k] = 8KB; wave w stages rows [w*32, w*32+32)
            llds16(kvTb + (size_t)(wave * 32 + srow) * FD_ + k0 + scol, Bs + (wave * 32) * 32);
            llds16(kvTb + (size_t)(wave * 32 + 16 + srow) * FD_ + k0 + scol, Bs + (wave * 32 + 16) * 32);
            __syncthreads();
            bf16x8 af = *(const bf16x8*)(H + (wave * 16 + arow_rd) * 264 + k0 + kgrp);
#pragma unroll
            for (int nt = 0; nt < 8; nt++) {
                bf16x8 bg = *(const bf16x8*)(Bs + (nt * 16 + arow_rd) * 32 + kgrp);
                pacc[nt] = __builtin_amdgcn_mfma_f32_16x16x32_bf16(af, bg, pacc[nt], 0, 0, 0);
            }
            __syncthreads();
        }
        // divide + bounce via H rows [0..63][0..127], then coalesced stores
        const int rbase = (lane >> 4) << 2, cl = lane & 15;
#pragma unroll
        for (int nt = 0; nt < 8; nt++)
#pragma unroll
            for (int r = 0; r < 4; r++) {
                int row = wave * 16 + rbase + r;
                H[row * 264 + nt * 16 + cl] = f2bf(pacc[nt][r] * RD[row]);
            }
        __syncthreads();
        const int b = bh >> 4, h = bh & 15, lb = mb & 4095;
        const int c8 = (tid & 15) * 8;
#pragma unroll
        for (int it = 0; it < 4; it++) {
            int row = (tid >> 4) + it * 16;
            uint2 lo = *(const uint2*)(H + row * 264 + c8);
            uint2 hi = *(const uint2*)(H + row * 264 + c8 + 4);
            *(uint4*)(attnOut + ((size_t)(b * L_ + lb + row)) * HS_ + h * HD_ + c8) =
                make_uint4(lo.x, lo.y, hi.x, hi.y);
        }
    } else {
        // write featT[bh][f][l] + ksum partial per (block, f)
        int f = tid;
        int bh = mb >> 12, lb = mb & 4095;
        float gf = g[f], bf = be[f];
        u16* orow = feat + ((size_t)bh * FD_ + f) * L_ + lb;
        float fsum = 0.f;
        for (int lg = 0; lg < 64; lg += 8) {
            union { u16 h8[8]; uint4 v4; } pk;
#pragma unroll
            for (int j = 0; j < 8; j++) {
                int row = lg + j;
                float x = bf2f(H[row * 264 + f]);
                float y = ((x - MU[row]) * RS[row] * gf + bf) * FAC[row];
                fsum += y;
                pk.h8[j] = f2bf(y);
            }
            *(uint4*)(orow + lg) = pk.v4;
        }
        ksp[((size_t)bh * 64 + (lb >> 6)) * FD_ + f] = fsum;
    }
}

// reduce 64 per-block partials -> ksum[bh][f]
__global__ __launch_bounds__(256) void k_ksum2(const float* __restrict__ ksp, float* __restrict__ ksum) {
    const int bh = blockIdx.x, f = threadIdx.x;
    float s = 0.f;
    for (int i = 0; i < 64; i++) s += ksp[((size_t)bh * 64 + i) * FD_ + f];
    ksum[(size_t)bh * FD_ + f] = s;
}

// ---------------------------------------------------------------------------
// kv GEMM: per (f-block, k-slice, bh): kfT[256,4096] @ vT[128,4096]^T
// fp32 partials [ks*32+bh][f][d]; K split 4-way (256 blocks = 1 round)
// ---------------------------------------------------------------------------
__global__ __launch_bounds__(256) void k_gemm_kv(const u16* __restrict__ kfT, const u16* __restrict__ vT,
                                                 float* __restrict__ kvp) {
    __shared__ u16 As[4096], Bs[4096];
    f32x4 acc[4][4];
    const int mb = blockIdx.x * 128;    // f block (0..1)
    const int ks = blockIdx.y;          // k slice (0..3), 1024 each
    const int bh = blockIdx.z;
    gemm_mainloop(kfT + ((size_t)bh * FD_ + mb) * L_ + ks * 1024, L_,
                  vT + (size_t)bh * HD_ * L_ + ks * 1024, L_, 1024, As, Bs, acc);
    const int lane = threadIdx.x & 63, wave = threadIdx.x >> 6;
    const int wm = wave >> 1, wn = wave & 1;
    const int n0 = wn * 64 + (lane & 15);
    const int m0 = mb + wm * 64 + ((lane >> 4) << 2);
    float* o = kvp + (size_t)(ks * 32 + bh) * (FD_ * HD_);
#pragma unroll
    for (int nt = 0; nt < 4; nt++)
#pragma unroll
        for (int mt = 0; mt < 4; mt++)
#pragma unroll
            for (int r = 0; r < 4; r++)
                o[(size_t)(m0 + mt * 16 + r) * HD_ + n0 + nt * 16] = acc[mt][nt][r];
}

// reduce 4 k-slice partials -> kvT[bh][d][f] bf16
__global__ __launch_bounds__(256) void k_kvred(const float* __restrict__ kvp, u16* __restrict__ kvT) {
    const int p = blockIdx.x, bh = blockIdx.y, t = threadIdx.x;
    const int e0 = p * 4096 + t * 16;
    float s[16];
#pragma unroll
    for (int i = 0; i < 16; i++) s[i] = 0.f;
    for (int c = 0; c < 4; c++) {
        const float* src = kvp + ((size_t)(c * 32 + bh)) * 32768 + e0;
#pragma unroll
        for (int i = 0; i < 16; i += 4) {
            float4 vv = *(const float4*)(src + i);
            s[i] += vv.x; s[i + 1] += vv.y; s[i + 2] += vv.z; s[i + 3] += vv.w;
        }
    }
#pragma unroll
    for (int i = 0; i < 16; i++) {
        int e = e0 + i, fq = e >> 7, d = e & 127;
        kvT[((size_t)bh * HD_ + d) * FD_ + fq] = f2bf(s[i]);
    }
}

// ---------------------------------------------------------------------------
// workspace layout (bytes), total ~237 MiB.  Launch order:
//   cvt -> transpose -> qkv -> feat<k> -> ksum2 -> gemm_kv -> kvred
//   -> feat<q>(attn fused) -> out
//   [0]          Wqkv_t 25,165,824 then Xbf 33,554,432 (dead after qkv)
//   [67108864]   kfT   67,108,864   ([bh][f][l])
//   [134217728]  qbuf  33,554,432   (live until feat<q>)
//   [167772160]  kbuf  33,554,432   -> kvp (16.8MB fp32, after feat<k>)
//                                   -> attn (after kvred consumes kvp)
//   [201326592]  vT    33,554,432   ([bh][d][l])
//   [234881024]  Wo_t   8,388,608
//   [243269632]  Wf1_t     65,536
//   [243335168]  Wf2_t    131,072
//   [243466240]  ksp    2,097,152
//   [245563392]  kvT    2,097,152
//   [247660544]  ksum      32,768   -> end 247,693,312
// ---------------------------------------------------------------------------
extern "C" void kernel_launch(void* const* d_in, const int* in_sizes, int n_in,
                              void* d_out, int out_size, void* d_ws, size_t ws_size,
                              hipStream_t stream) {
    const float* hs  = (const float*)d_in[0];
    const float* msk = (const float*)d_in[1];
    const float* Wq  = (const float*)d_in[2];  const float* bq  = (const float*)d_in[3];
    const float* Wk  = (const float*)d_in[4];  const float* bk  = (const float*)d_in[5];
    const float* Wv  = (const float*)d_in[6];  const float* bv  = (const float*)d_in[7];
    const float* Wo  = (const float*)d_in[8];  const float* bo  = (const float*)d_in[9];
    const float* Wf1 = (const float*)d_in[10]; const float* bf1 = (const float*)d_in[11];
    const float* Wf2 = (const float*)d_in[12]; const float* bf2 = (const float*)d_in[13];
    const float* lng = (const float*)d_in[14]; const float* lnb = (const float*)d_in[15];
    float* out = (float*)d_out;
    char* w = (char*)d_ws;

    u16* Wqkv_t = (u16*)(w + 0);               // dead after qkv
    u16* Xbf    = (u16*)(w + 25165824u);       // dead after qkv
    u16* kfT    = (u16*)(w + 67108864u);
    u16* qbuf   = (u16*)(w + 134217728u);
    u16* kbuf   = (u16*)(w + 167772160u);
    float* kvp  = (float*)(w + 167772160u);    // alias: kbuf dead after feat<k>
    u16* attn   = (u16*)(w + 167772160u);      // alias: kvp dead after kvred
    u16* vT     = (u16*)(w + 201326592u);
    u16* Wo_t   = (u16*)(w + 234881024u);
    u16* Wf1_t  = (u16*)(w + 243269632u);
    u16* Wf2_t  = (u16*)(w + 243335168u);
    float* ksp  = (float*)(w + 243466240u);
    u16* kvT    = (u16*)(w + 245563392u);
    float* ksum = (float*)(w + 247660544u);

    k_cvt<<<dim3(8192), 256, 0, stream>>>(hs, Xbf);
    k_transpose<<<dim3(64, 64, 6), dim3(32, 8), 0, stream>>>(Wq, Wk, Wv, Wo, Wf1, Wf2,
                                                             Wqkv_t, Wo_t, Wf1_t, Wf2_t);
    k_gemm_qkv<<<dim3(768), 512, 0, stream>>>(Xbf, Wqkv_t, bq, bk, bv, qbuf, kbuf, vT);
    // k-chain first so ksum + kvT are ready before feat<q> (attn fused there)
    k_feat<1, 1><<<dim3(2048), 256, 0, stream>>>(kbuf, Wf1_t, bf1, Wf2_t, bf2, lng, lnb, msk,
                                                 nullptr, nullptr, kfT, ksp, nullptr);
    k_ksum2<<<dim3(32), 256, 0, stream>>>(ksp, ksum);
    k_gemm_kv<<<dim3(2, 4, 32), 256, 0, stream>>>(kfT, vT, kvp);
    k_kvred<<<dim3(8, 32), 256, 0, stream>>>(kvp, kvT);
    k_feat<0, 0><<<dim3(2048), 256, 0, stream>>>(qbuf, Wf1_t, bf1, Wf2_t, bf2, lng, lnb, msk,
                                                 ksum, kvT, nullptr, nullptr, attn);
    k_gemm_out<<<dim3(256), 512, 0, stream>>>(attn, Wo_t, bo, out);
}

// Round 8
// 657.505 us; speedup vs baseline: 1.0518x; 1.0210x over previous
//
#include <hip/hip_runtime.h>

typedef unsigned short u16;
typedef unsigned int u32;
typedef __attribute__((ext_vector_type(8))) short bf16x8;
typedef __attribute__((ext_vector_type(4))) float f32x4;

#define B_ 2
#define L_ 4096
#define HS_ 2048
#define NH_ 16
#define HD_ 128
#define FD_ 256

__device__ __forceinline__ float bf2f(u16 u) { return __uint_as_float(((u32)u) << 16); }
__device__ __forceinline__ u16 f2bf(float f) {
    u32 x = __float_as_uint(f);
    return (u16)((x + 0x7fffu + ((x >> 16) & 1u)) >> 16);
}

// async global->LDS, 16B per lane; LDS dest = wave-uniform base + lane*16
__device__ __forceinline__ void llds16(const u16* g, u16* l) {
    __builtin_amdgcn_global_load_lds((const __attribute__((address_space(1))) void*)g,
                                     (__attribute__((address_space(3))) void*)l, 16, 0, 0);
}

// ---------------------------------------------------------------------------
// Shared MFMA mainloop: C[128x128] block, 4 waves (2x2), 16x16x32 bf16 MFMA.
// A: [M,K] row-major bf16. Bt: [N,K] row-major bf16. LDS tiles [128][32].
// (used by the kv gemm)
// ---------------------------------------------------------------------------
__device__ __forceinline__ void gemm_mainloop(const u16* __restrict__ Ab, int lda,
                                              const u16* __restrict__ Bb, int ldb,
                                              int K, u16* As, u16* Bs, f32x4 (&acc)[4][4]) {
    const int tid  = threadIdx.x;
    const int lane = tid & 63;
    const int wave = tid >> 6;
    const int wm = wave >> 1, wn = wave & 1;

    f32x4 zero = {0.f, 0.f, 0.f, 0.f};
#pragma unroll
    for (int i = 0; i < 4; i++)
#pragma unroll
        for (int j = 0; j < 4; j++) acc[i][j] = zero;

    const int srow = lane >> 2;
    const int scol = (lane & 3) * 8;
    const u16* pa = Ab + (size_t)(wave * 32 + srow) * lda + scol;
    const u16* pb = Bb + (size_t)(wave * 32 + srow) * ldb + scol;
    u16* la = As + wave * 1024;
    u16* lb = Bs + wave * 1024;

    const int arow = (wm * 64 + (lane & 15)) * 32 + (lane >> 4) * 8;
    const int brow = (wn * 64 + (lane & 15)) * 32 + (lane >> 4) * 8;

    for (int k0 = 0; k0 < K; k0 += 32) {
        llds16(pa, la);
        llds16(pa + 16 * lda, la + 512);
        llds16(pb, lb);
        llds16(pb + 16 * ldb, lb + 512);
        pa += 32; pb += 32;
        __syncthreads();
        bf16x8 af[4], bg[4];
#pragma unroll
        for (int mt = 0; mt < 4; mt++) af[mt] = *(const bf16x8*)(As + arow + mt * 512);
#pragma unroll
        for (int nt = 0; nt < 4; nt++) bg[nt] = *(const bf16x8*)(Bs + brow + nt * 512);
#pragma unroll
        for (int mt = 0; mt < 4; mt++)
#pragma unroll
            for (int nt = 0; nt < 4; nt++)
                acc[mt][nt] = __builtin_amdgcn_mfma_f32_16x16x32_bf16(af[mt], bg[nt], acc[mt][nt], 0, 0, 0);
        __syncthreads();
    }
}

// ---------------------------------------------------------------------------
// fp32 -> bf16 bulk convert (hidden_states -> Xbf). n multiple of 2048.
// ---------------------------------------------------------------------------
__global__ __launch_bounds__(256) void k_cvt(const float* __restrict__ src, u16* __restrict__ dst) {
    size_t i = ((size_t)blockIdx.x * 256 + threadIdx.x) * 8;
    float4 a = *(const float4*)(src + i);
    float4 b = *(const float4*)(src + i + 4);
    union { u16 h[8]; uint4 v; } o;
    o.h[0] = f2bf(a.x); o.h[1] = f2bf(a.y); o.h[2] = f2bf(a.z); o.h[3] = f2bf(a.w);
    o.h[4] = f2bf(b.x); o.h[5] = f2bf(b.y); o.h[6] = f2bf(b.z); o.h[7] = f2bf(b.w);
    *(uint4*)(dst + i) = o.v;
}

// ---------------------------------------------------------------------------
// Weight transposes + fp32->bf16: W[k][n] fp32 -> Wt[n][k] bf16
// ---------------------------------------------------------------------------
__global__ __launch_bounds__(256) void k_transpose(const float* Wq, const float* Wk, const float* Wv,
                                                   const float* Wo, const float* Wf1, const float* Wf2,
                                                   u16* Wqkv_t, u16* Wo_t, u16* Wf1_t, u16* Wf2_t) {
    const float* src; u16* dst; int R, C;
    switch (blockIdx.z) {
        case 0: src = Wq;  dst = Wqkv_t;                R = 2048; C = 2048; break;
        case 1: src = Wk;  dst = Wqkv_t + 2048 * 2048;  R = 2048; C = 2048; break;
        case 2: src = Wv;  dst = Wqkv_t + 2 * 2048 * 2048; R = 2048; C = 2048; break;
        case 3: src = Wo;  dst = Wo_t;                  R = 2048; C = 2048; break;
        case 4: src = Wf1; dst = Wf1_t;                 R = 128;  C = 256;  break;
        default: src = Wf2; dst = Wf2_t;                R = 256;  C = 256;  break;
    }
    int c0 = blockIdx.x * 32, r0 = blockIdx.y * 32;
    if (c0 >= C || r0 >= R) return;
    __shared__ u16 tile[32][33];
    int tx = threadIdx.x, ty = threadIdx.y;
    for (int i = ty; i < 32; i += 8) tile[i][tx] = f2bf(src[(size_t)(r0 + i) * C + c0 + tx]);
    __syncthreads();
    for (int i = ty; i < 32; i += 8) dst[(size_t)(c0 + i) * R + r0 + tx] = tile[tx][i];
}

// ---------------------------------------------------------------------------
// 256x256 8-phase mainloop template (T1+T2+T3+T4+T5), K=2048, stride 2048.
// (unchanged — see round-1 comments for the schedule derivation)
// ---------------------------------------------------------------------------
#define QKV_BAR() { __builtin_amdgcn_sched_barrier(0); __builtin_amdgcn_s_barrier(); \
                    __builtin_amdgcn_sched_barrier(0); }
#define QKV_LGKM0() { asm volatile("s_waitcnt lgkmcnt(0)" ::: "memory"); \
                      __builtin_amdgcn_sched_barrier(0); }

__device__ __forceinline__ void mainloop256(const u16* __restrict__ Abase,
                                            const u16* __restrict__ Bbase,
                                            u16* LDS, f32x4 (&acc)[8][4]) {
    const int tid = threadIdx.x, lane = tid & 63, wave = tid >> 6;
    const int wm = wave >> 2, wn = wave & 3;

    // staging source coords (inverse st_16x32 swizzle). Half-tile = 128x64 bf16
    // = 16 subtiles of [16 rows][32 cols] (1024B). j=0 -> subtiles 0-7, j=1 -> 8-15.
    int r0g, c0g, r1g, c1g;
    { int p = tid * 16; int s = p >> 10, q = p & 1023; q ^= ((q >> 9) & 1) << 5;
      r0g = (s >> 1) * 16 + (q >> 6); c0g = (s & 1) * 32 + ((q & 63) >> 1); }
    { int p = 8192 + tid * 16; int s = p >> 10, q = p & 1023; q ^= ((q >> 9) & 1) << 5;
      r1g = (s >> 1) * 16 + (q >> 6); c1g = (s & 1) * 32 + ((q & 63) >> 1); }
    const int voff0 = r0g * HS_ + c0g;
    const int voff1 = r1g * HS_ + c1g;

    // read-side swizzled in-subtile offset (u16 units): row=lane&15, 16B chunk=(lane>>4)
    int qby = (lane & 15) * 64 + (lane >> 4) * 16;
    qby ^= ((qby >> 9) & 1) << 5;
    const int qh = qby >> 1;

#define STG(G, soff, dstu) { \
    llds16((G) + (soff) + voff0, LDS + (dstu) + wave * 512); \
    llds16((G) + (soff) + voff1, LDS + (dstu) + 4096 + wave * 512); }

    const size_t a0 = 0, a1 = (size_t)128 * HS_;
    const size_t b0 = 0, b1 = (size_t)128 * HS_;

    // prologue: tile0 {B0,B1,A0,A1} + tile1 {B0,B1,A0}; A1(1) staged at t=0 P1.
    STG(Bbase, b0, 32768); STG(Bbase, b1, 40960);
    STG(Abase, a0, 0);     STG(Abase, a1, 8192);
    STG(Bbase, b0 + 64, 49152); STG(Bbase, b1 + 64, 57344);
    STG(Abase, a0 + 64, 16384);
    asm volatile("s_waitcnt vmcnt(6)" ::: "memory");   // tile0 complete
    QKV_BAR();

    f32x4 zero = {0.f, 0.f, 0.f, 0.f};
#pragma unroll
    for (int i = 0; i < 8; i++)
#pragma unroll
        for (int j = 0; j < 4; j++) acc[i][j] = zero;

    const int NT = HS_ / 64;   // 32
    bf16x8 afr[4][2], bfr[4][2];
    for (int t = 0; t < NT; t++) {
        const int bsel = t & 1;
        const u16* Ah = LDS + bsel * 16384 + wm * 8192;
        const u16* Bh = LDS + 32768 + bsel * 16384 + (wn >> 1) * 8192;
        const int bg0 = (wn & 1) * 4;
        const size_t kc1 = (size_t)(t + 1) * 64, kc2 = (size_t)(t + 2) * 64;

        // ---- phase 1 ----
#pragma unroll
        for (int mf = 0; mf < 4; mf++)
#pragma unroll
            for (int ks = 0; ks < 2; ks++)
                afr[mf][ks] = *(const bf16x8*)(Ah + (mf * 2 + ks) * 512 + qh);
#pragma unroll
        for (int nf = 0; nf < 4; nf++)
#pragma unroll
            for (int ks = 0; ks < 2; ks++)
                bfr[nf][ks] = *(const bf16x8*)(Bh + ((bg0 + nf) * 2 + ks) * 512 + qh);
        if (t + 1 < NT) STG(Abase, a1 + kc1, (bsel ^ 1) * 16384 + 8192);    // A1(t+1)
        QKV_BAR();
        QKV_LGKM0();
        __builtin_amdgcn_s_setprio(1);
#pragma unroll
        for (int mf = 0; mf < 4; mf++)
#pragma unroll
            for (int nf = 0; nf < 2; nf++)
#pragma unroll
                for (int ks = 0; ks < 2; ks++)
                    acc[mf][nf] = __builtin_amdgcn_mfma_f32_16x16x32_bf16(afr[mf][ks], bfr[nf][ks], acc[mf][nf], 0, 0, 0);
        __builtin_amdgcn_s_setprio(0);
        QKV_BAR();
        // ---- phase 2 ----
        if (t + 2 < NT) STG(Bbase, b0 + kc2, 32768 + bsel * 16384);        // B0(t+2)
        QKV_BAR();
        __builtin_amdgcn_s_setprio(1);
#pragma unroll
        for (int mf = 0; mf < 4; mf++)
#pragma unroll
            for (int nf = 2; nf < 4; nf++)
#pragma unroll
                for (int ks = 0; ks < 2; ks++)
                    acc[mf][nf] = __builtin_amdgcn_mfma_f32_16x16x32_bf16(afr[mf][ks], bfr[nf][ks], acc[mf][nf], 0, 0, 0);
        __builtin_amdgcn_s_setprio(0);
        QKV_BAR();
        // ---- phase 3 ----
#pragma unroll
        for (int mf = 0; mf < 4; mf++)
#pragma unroll
            for (int ks = 0; ks < 2; ks++)
                afr[mf][ks] = *(const bf16x8*)(Ah + ((mf + 4) * 2 + ks) * 512 + qh);
        if (t + 2 < NT) STG(Bbase, b1 + kc2, 32768 + bsel * 16384 + 8192); // B1(t+2)
        QKV_BAR();
        QKV_LGKM0();
        __builtin_amdgcn_s_setprio(1);
#pragma unroll
        for (int mf = 0; mf < 4; mf++)
#pragma unroll
            for (int nf = 0; nf < 2; nf++)
#pragma unroll
                for (int ks = 0; ks < 2; ks++)
                    acc[mf + 4][nf] = __builtin_amdgcn_mfma_f32_16x16x32_bf16(afr[mf][ks], bfr[nf][ks], acc[mf + 4][nf], 0, 0, 0);
        __builtin_amdgcn_s_setprio(0);
        QKV_BAR();
        // ---- phase 4 ----
        if (t + 2 < NT) STG(Abase, a0 + kc2, bsel * 16384);                 // A0(t+2)
        QKV_BAR();
        __builtin_amdgcn_s_setprio(1);
#pragma unroll
        for (int mf = 0; mf < 4; mf++)
#pragma unroll
            for (int nf = 2; nf < 4; nf++)
#pragma unroll
                for (int ks = 0; ks < 2; ks++)
                    acc[mf + 4][nf] = __builtin_amdgcn_mfma_f32_16x16x32_bf16(afr[mf][ks], bfr[nf][ks], acc[mf + 4][nf], 0, 0, 0);
        __builtin_amdgcn_s_setprio(0);
        if (t + 2 < NT) { asm volatile("s_waitcnt vmcnt(6)" ::: "memory"); }
        else if (t + 1 < NT) { asm volatile("s_waitcnt vmcnt(0)" ::: "memory"); }
        QKV_BAR();
    }
#undef STG
}

// ---------------------------------------------------------------------------
// QKV gemm: Xbf[8192,2048] @ Wqkv_t[6144,2048]^T + bias ->
//   q,k:[bh][l][d], vT:[bh][d][l]; bijective XCD chunking (4m x 24n / XCD).
// (R4 mapping: lowest measured FETCH=147MB and best measured dur)
// ---------------------------------------------------------------------------
__global__ __launch_bounds__(512, 2) void k_gemm_qkv(
        const u16* __restrict__ X, const u16* __restrict__ Wt,
        const float* __restrict__ bq, const float* __restrict__ bk, const float* __restrict__ bv,
        u16* __restrict__ qout, u16* __restrict__ kout, u16* __restrict__ vT) {
    __shared__ u16 LDS[65536];                 // 128 KB: A bufs [0,32768), B bufs [32768,65536)
    const int tid = threadIdx.x, lane = tid & 63, wave = tid >> 6;
    const int wm = wave >> 2, wn = wave & 3;

    // bijective XCD chunking: 768 blocks = 8 XCDs x (24 n x 4 m)
    const int xcd = blockIdx.x & 7, idx = blockIdx.x >> 3;
    const int nblk = idx >> 2;                 // 0..23
    const int mblk = xcd * 4 + (idx & 3);      // 0..31
    const int mb = mblk * 256, nb = nblk * 256;

    f32x4 acc[8][4];
    mainloop256(X + (size_t)mb * HS_, Wt + (size_t)nb * HS_, LDS, acc);

    // ---- epilogue: LDS-bounce, 2 half-passes (rows 0-127 / 128-255) ----
    const int which = nblk >> 3;                 // 0=q,1=k,2=v
    const int colbase = (nblk & 7) * 256;        // column within the 2048-wide output
    const int bi = mb >> 12, lb = mb & 4095;
    const float* bias = (which == 0) ? bq : (which == 1 ? bk : bv);
    const int rb = (lane >> 4) << 2, cl = lane & 15;

    if (which < 2) {
        u16* dst = (which == 0) ? qout : kout;
        const int bh0 = bi * NH_ + (colbase >> 7);
        for (int half = 0; half < 2; half++) {
            if (wm == half) {
#pragma unroll
                for (int nf = 0; nf < 4; nf++) {
                    float bvv = bias[colbase + wn * 64 + nf * 16 + cl];
#pragma unroll
                    for (int mf = 0; mf < 8; mf++)
#pragma unroll
                        for (int r2 = 0; r2 < 4; r2++)
                            LDS[(mf * 16 + rb + r2) * 264 + wn * 64 + nf * 16 + cl] =
                                f2bf(acc[mf][nf][r2] + bvv);
                }
            }
            __syncthreads();
#pragma unroll
            for (int it = 0; it < 8; it++) {
                int row = (tid >> 5) + it * 16;
                int c8 = (tid & 31) * 8;
                uint2 lo = *(const uint2*)(LDS + row * 264 + c8);
                uint2 hi = *(const uint2*)(LDS + row * 264 + c8 + 4);
                uint4 val = make_uint4(lo.x, lo.y, hi.x, hi.y);
                u16* pp = dst + ((size_t)(bh0 + (c8 >> 7)) * L_ + lb + half * 128 + row) * HD_ + (c8 & 127);
                *(uint4*)pp = val;
            }
            __syncthreads();
        }
    } else {
        for (int half = 0; half < 2; half++) {
            if (wm == half) {
#pragma unroll
                for (int nf = 0; nf < 4; nf++) {
                    float bvv = bias[colbase + wn * 64 + nf * 16 + cl];
#pragma unroll
                    for (int mf = 0; mf < 8; mf++)
#pragma unroll
                        for (int r2 = 0; r2 < 4; r2++)
                            LDS[(wn * 64 + nf * 16 + cl) * 136 + mf * 16 + rb + r2] =
                                f2bf(acc[mf][nf][r2] + bvv);
                }
            }
            __syncthreads();
#pragma unroll
            for (int it = 0; it < 8; it++) {
                int n = (tid >> 4) + it * 32;
                int c8 = (tid & 15) * 8;
                uint2 lo = *(const uint2*)(LDS + n * 136 + c8);
                uint2 hi = *(const uint2*)(LDS + n * 136 + c8 + 4);
                uint4 val = make_uint4(lo.x, lo.y, hi.x, hi.y);
                int cg = colbase + n;
                u16* pp = vT + ((size_t)(bi * NH_ + (cg >> 7)) * HD_ + (cg & 127)) * L_ + lb + half * 128 + c8;
                *(uint4*)pp = val;
            }
            __syncthreads();
        }
    }
}

// ---------------------------------------------------------------------------
// final projection, 256x256 8-phase: attn[8192,2048] @ Wo_t[2048,2048]^T + bo
// -> out fp32. 256 blocks = 1/CU; nblk=xcd (Wo panel L2-resident per XCD).
// ---------------------------------------------------------------------------
__global__ __launch_bounds__(512, 2) void k_gemm_out(const u16* __restrict__ A, const u16* __restrict__ Wt,
                                                     const float* __restrict__ bo, float* __restrict__ out) {
    __shared__ u16 LDS[65536];
    const int lane = threadIdx.x & 63, wave = threadIdx.x >> 6;
    const int wm = wave >> 2, wn = wave & 3;

    const int xcd = blockIdx.x & 7, idx = blockIdx.x >> 3;
    const int nblk = xcd;                      // 0..7
    const int mblk = idx;                      // 0..31
    const int mb = mblk * 256, nb = nblk * 256;

    f32x4 acc[8][4];
    mainloop256(A + (size_t)mb * HS_, Wt + (size_t)nb * HS_, LDS, acc);

    const int rb = (lane >> 4) << 2, cl = lane & 15;
#pragma unroll
    for (int nf = 0; nf < 4; nf++) {
        int n = nb + wn * 64 + nf * 16 + cl;
        float bvv = bo[n];
#pragma unroll
        for (int mf = 0; mf < 8; mf++) {
            int m = mb + wm * 128 + mf * 16 + rb;
#pragma unroll
            for (int r = 0; r < 4; r++)
                out[(size_t)(m + r) * HS_ + n] = acc[mf][nf][r] + bvv;
        }
    }
}

// ---------------------------------------------------------------------------
// Fused feature map, BK=64 (halved barrier count vs BK=32).
// LDS A/B layout: two [rows][32] subtiles, ks-major (linear gload_lds dest;
// ds_read pattern per subtile identical to the BK=32 version).
// TRANS=1 (k path): writes featT[bh][f][l] + per-block ksum partials.
// TRANS=0 (q path): qf written back into H; inline 1/denom; fused attn
// numerator GEMM qf[64,256] @ kvT[bh][128,256]^T; direct attn stores.
// Numerics: per-acc k-ascending MFMA chain unchanged -> bitwise identical.
// ---------------------------------------------------------------------------
template <int MASKED, int TRANS>
__global__ __launch_bounds__(256) void k_feat(const u16* __restrict__ X,
                                              const u16* __restrict__ W1t, const float* __restrict__ b1,
                                              const u16* __restrict__ W2t, const float* __restrict__ b2,
                                              const float* __restrict__ g, const float* __restrict__ be,
                                              const float* __restrict__ mask, const float* __restrict__ ksum,
                                              const u16* __restrict__ kvT,
                                              u16* __restrict__ feat, float* __restrict__ ksp,
                                              u16* __restrict__ attnOut) {
    __shared__ u16 As[2 * 2048];    // [ks][64][32]  = 8 KB
    __shared__ u16 Bs[2 * 8192];    // [ks][256][32] = 32 KB
    __shared__ u16 H[64 * 264];
    __shared__ float MU[64], RS[64], FAC[64], RD[64];
    const int tid = threadIdx.x, lane = tid & 63, wave = tid >> 6;
    const int mb = blockIdx.x * 64;

    const int srow = lane >> 2, scol = (lane & 3) * 8;   // 16-row stage coords
    const int arow_rd = (lane & 15);
    const int kgrp = (lane >> 4) * 8;

    f32x4 acc[4][4];
    f32x4 zero = {0.f, 0.f, 0.f, 0.f};
#pragma unroll
    for (int i = 0; i < 4; i++)
#pragma unroll
        for (int j = 0; j < 4; j++) acc[i][j] = zero;

    // ---- GEMM1: x[64,128] @ W1t[256,128]^T, BK=64 (2 steps) ----
    for (int k0 = 0; k0 < 128; k0 += 64) {
#pragma unroll
        for (int ks = 0; ks < 2; ks++)
            llds16(X + (size_t)(mb + wave * 16 + srow) * 128 + k0 + ks * 32 + scol,
                   As + ks * 2048 + wave * 512);
#pragma unroll
        for (int i = 0; i < 8; i++) {
            int ks = i & 1, rg = i >> 1;
            llds16(W1t + (size_t)(wave * 64 + rg * 16 + srow) * 128 + k0 + ks * 32 + scol,
                   Bs + ks * 8192 + wave * 2048 + rg * 512);
        }
        __syncthreads();
        bf16x8 af[4][2], bg[4][2];
#pragma unroll
        for (int mt = 0; mt < 4; mt++)
#pragma unroll
            for (int ks = 0; ks < 2; ks++)
                af[mt][ks] = *(const bf16x8*)(As + ks * 2048 + (mt * 16 + arow_rd) * 32 + kgrp);
#pragma unroll
        for (int nt = 0; nt < 4; nt++)
#pragma unroll
            for (int ks = 0; ks < 2; ks++)
                bg[nt][ks] = *(const bf16x8*)(Bs + ks * 8192 + (wave * 64 + nt * 16 + arow_rd) * 32 + kgrp);
#pragma unroll
        for (int mt = 0; mt < 4; mt++)
#pragma unroll
            for (int nt = 0; nt < 4; nt++)
#pragma unroll
                for (int ks = 0; ks < 2; ks++)
                    acc[mt][nt] = __builtin_amdgcn_mfma_f32_16x16x32_bf16(af[mt][ks], bg[nt][ks], acc[mt][nt], 0, 0, 0);
        __syncthreads();
    }
    {
        const int rbase = (lane >> 4) << 2;
#pragma unroll
        for (int nt = 0; nt < 4; nt++) {
            int n = wave * 64 + nt * 16 + (lane & 15);
            float bvv = b1[n];
#pragma unroll
            for (int mt = 0; mt < 4; mt++)
#pragma unroll
                for (int r = 0; r < 4; r++) {
                    float v = fmaxf(acc[mt][nt][r] + bvv, 0.f);
                    H[(mt * 16 + rbase + r) * 264 + n] = f2bf(v);
                }
            acc[0][nt] = zero; acc[1][nt] = zero; acc[2][nt] = zero; acc[3][nt] = zero;
        }
    }
    __syncthreads();

    // ---- GEMM2: h1[64,256] @ W2t[256,256]^T, BK=64 (4 steps) ----
    for (int k0 = 0; k0 < 256; k0 += 64) {
#pragma unroll
        for (int i = 0; i < 8; i++) {
            int ks = i & 1, rg = i >> 1;
            llds16(W2t + (size_t)(wave * 64 + rg * 16 + srow) * 256 + k0 + ks * 32 + scol,
                   Bs + ks * 8192 + wave * 2048 + rg * 512);
        }
        __syncthreads();
        bf16x8 af[4][2], bg[4][2];
#pragma unroll
        for (int mt = 0; mt < 4; mt++)
#pragma unroll
            for (int ks = 0; ks < 2; ks++)
                af[mt][ks] = *(const bf16x8*)(H + (mt * 16 + arow_rd) * 264 + k0 + ks * 32 + kgrp);
#pragma unroll
        for (int nt = 0; nt < 4; nt++)
#pragma unroll
            for (int ks = 0; ks < 2; ks++)
                bg[nt][ks] = *(const bf16x8*)(Bs + ks * 8192 + (wave * 64 + nt * 16 + arow_rd) * 32 + kgrp);
#pragma unroll
        for (int mt = 0; mt < 4; mt++)
#pragma unroll
            for (int nt = 0; nt < 4; nt++)
#pragma unroll
                for (int ks = 0; ks < 2; ks++)
                    acc[mt][nt] = __builtin_amdgcn_mfma_f32_16x16x32_bf16(af[mt][ks], bg[nt][ks], acc[mt][nt], 0, 0, 0);
        __syncthreads();
    }
    {
        const int rbase = (lane >> 4) << 2;
#pragma unroll
        for (int nt = 0; nt < 4; nt++) {
            int n = wave * 64 + nt * 16 + (lane & 15);
            float bvv = b2[n];
#pragma unroll
            for (int mt = 0; mt < 4; mt++)
#pragma unroll
                for (int r = 0; r < 4; r++)
                    H[(mt * 16 + rbase + r) * 264 + n] = f2bf(acc[mt][nt][r] + bvv);
        }
    }
    __syncthreads();

    // ---- LayerNorm stats ----
    {
        for (int r = 0; r < 16; r++) {
            int row = wave * 16 + r;
            int j = lane * 4;
            uint2 u = *(const uint2*)(H + row * 264 + j);
            float x0 = bf2f((u16)(u.x & 0xffff)), x1 = bf2f((u16)(u.x >> 16));
            float x2 = bf2f((u16)(u.y & 0xffff)), x3 = bf2f((u16)(u.y >> 16));
            float s = x0 + x1 + x2 + x3;
            float ss = x0 * x0 + x1 * x1 + x2 * x2 + x3 * x3;
#pragma unroll
            for (int o = 32; o >= 1; o >>= 1) { s += __shfl_xor(s, o); ss += __shfl_xor(ss, o); }
            if (lane == 0) {
                float mu = s * (1.f / FD_);
                float var = ss * (1.f / FD_) - mu * mu;
                MU[row] = mu;
                RS[row] = rsqrtf(var + 1e-5f);
                float fac = 1.f;
                if (MASKED) {
                    int grow = mb + row;
                    int b = grow >> 16;
                    int l = grow & 4095;
                    fac = 1.f + mask[b * L_ + l];
                }
                FAC[row] = fac;
            }
        }
    }
    __syncthreads();

    if (!TRANS) {
        const int bh = mb >> 12;
        const u16* kvTb = kvT + (size_t)bh * HD_ * FD_;
        // LN -> qf bf16 written back into H; per-row 1/denom into RD
        {
            int j = lane * 4;
            float4 gg = *(const float4*)(g + j);
            float4 bb = *(const float4*)(be + j);
            float4 kk = *(const float4*)(ksum + (size_t)bh * FD_ + j);
            for (int r = 0; r < 16; r++) {
                int row = wave * 16 + r;
                float mu = MU[row], rstd = RS[row], fac = FAC[row];
                uint2 u = *(const uint2*)(H + row * 264 + j);
                float x0 = bf2f((u16)(u.x & 0xffff)), x1 = bf2f((u16)(u.x >> 16));
                float x2 = bf2f((u16)(u.y & 0xffff)), x3 = bf2f((u16)(u.y >> 16));
                u16 h0 = f2bf(((x0 - mu) * rstd * gg.x + bb.x) * fac);
                u16 h1 = f2bf(((x1 - mu) * rstd * gg.y + bb.y) * fac);
                u16 h2 = f2bf(((x2 - mu) * rstd * gg.z + bb.z) * fac);
                u16 h3 = f2bf(((x3 - mu) * rstd * gg.w + bb.w) * fac);
                uint2 o2;
                o2.x = (u32)h0 | ((u32)h1 << 16);
                o2.y = (u32)h2 | ((u32)h3 << 16);
                *(uint2*)(H + row * 264 + j) = o2;
                float dp = bf2f(h0) * kk.x + bf2f(h1) * kk.y + bf2f(h2) * kk.z + bf2f(h3) * kk.w;
#pragma unroll
                for (int o = 32; o >= 1; o >>= 1) dp += __shfl_xor(dp, o);
                if (lane == 0) RD[row] = 1.f / (dp + 1e-8f);
            }
        }
        __syncthreads();   // qf-H + RD visible
        // ---- GEMM3: qf[64,256] @ kvT[bh][128,256]^T, BK=64 (4 steps) ----
        f32x4 pacc[8];
#pragma unroll
        for (int i = 0; i < 8; i++) pacc[i] = zero;
        for (int k0 = 0; k0 < 256; k0 += 64) {
#pragma unroll
            for (int i = 0; i < 4; i++) {
                int ks = i & 1, rg = i >> 1;
                llds16(kvTb + (size_t)(wave * 32 + rg * 16 + srow) * 256 + k0 + ks * 32 + scol,
                       Bs + ks * 4096 + wave * 1024 + rg * 512);
            }
            __syncthreads();
            bf16x8 af[2];
#pragma unroll
            for (int ks = 0; ks < 2; ks++)
                af[ks] = *(const bf16x8*)(H + (wave * 16 + arow_rd) * 264 + k0 + ks * 32 + kgrp);
#pragma unroll
            for (int nt = 0; nt < 8; nt++)
#pragma unroll
                for (int ks = 0; ks < 2; ks++) {
                    bf16x8 bg = *(const bf16x8*)(Bs + ks * 4096 + (nt * 16 + arow_rd) * 32 + kgrp);
                    pacc[nt] = __builtin_amdgcn_mfma_f32_16x16x32_bf16(af[ks], bg, pacc[nt], 0, 0, 0);
                }
            __syncthreads();
        }
        // divide + bounce via H rows [0..63][0..127], then coalesced stores
        const int rbase = (lane >> 4) << 2, cl = lane & 15;
#pragma unroll
        for (int nt = 0; nt < 8; nt++)
#pragma unroll
            for (int r = 0; r < 4; r++) {
                int row = wave * 16 + rbase + r;
                H[row * 264 + nt * 16 + cl] = f2bf(pacc[nt][r] * RD[row]);
            }
        __syncthreads();
        const int b = bh >> 4, h = bh & 15, lb = mb & 4095;
        const int c8 = (tid & 15) * 8;
#pragma unroll
        for (int it = 0; it < 4; it++) {
            int row = (tid >> 4) + it * 16;
            uint2 lo = *(const uint2*)(H + row * 264 + c8);
            uint2 hi = *(const uint2*)(H + row * 264 + c8 + 4);
            *(uint4*)(attnOut + ((size_t)(b * L_ + lb + row)) * HS_ + h * HD_ + c8) =
                make_uint4(lo.x, lo.y, hi.x, hi.y);
        }
    } else {
        // write featT[bh][f][l] + ksum partial per (block, f)
        int f = tid;
        int bh = mb >> 12, lb = mb & 4095;
        float gf = g[f], bf = be[f];
        u16* orow = feat + ((size_t)bh * FD_ + f) * L_ + lb;
        float fsum = 0.f;
        for (int lg = 0; lg < 64; lg += 8) {
            union { u16 h8[8]; uint4 v4; } pk;
#pragma unroll
            for (int j = 0; j < 8; j++) {
                int row = lg + j;
                float x = bf2f(H[row * 264 + f]);
                float y = ((x - MU[row]) * RS[row] * gf + bf) * FAC[row];
                fsum += y;
                pk.h8[j] = f2bf(y);
            }
            *(uint4*)(orow + lg) = pk.v4;
        }
        ksp[((size_t)bh * 64 + (lb >> 6)) * FD_ + f] = fsum;
    }
}

// reduce 64 per-block partials -> ksum[bh][f]
__global__ __launch_bounds__(256) void k_ksum2(const float* __restrict__ ksp, float* __restrict__ ksum) {
    const int bh = blockIdx.x, f = threadIdx.x;
    float s = 0.f;
    for (int i = 0; i < 64; i++) s += ksp[((size_t)bh * 64 + i) * FD_ + f];
    ksum[(size_t)bh * FD_ + f] = s;
}

// ---------------------------------------------------------------------------
// kv GEMM: per (f-block, k-slice, bh): kfT[256,4096] @ vT[128,4096]^T
// fp32 partials [ks*32+bh][f][d]; K split 4-way (256 blocks = 1 round)
// ---------------------------------------------------------------------------
__global__ __launch_bounds__(256) void k_gemm_kv(const u16* __restrict__ kfT, const u16* __restrict__ vT,
                                                 float* __restrict__ kvp) {
    __shared__ u16 As[4096], Bs[4096];
    f32x4 acc[4][4];
    const int mb = blockIdx.x * 128;    // f block (0..1)
    const int ks = blockIdx.y;          // k slice (0..3), 1024 each
    const int bh = blockIdx.z;
    gemm_mainloop(kfT + ((size_t)bh * FD_ + mb) * L_ + ks * 1024, L_,
                  vT + (size_t)bh * HD_ * L_ + ks * 1024, L_, 1024, As, Bs, acc);
    const int lane = threadIdx.x & 63, wave = threadIdx.x >> 6;
    const int wm = wave >> 1, wn = wave & 1;
    const int n0 = wn * 64 + (lane & 15);
    const int m0 = mb + wm * 64 + ((lane >> 4) << 2);
    float* o = kvp + (size_t)(ks * 32 + bh) * (FD_ * HD_);
#pragma unroll
    for (int nt = 0; nt < 4; nt++)
#pragma unroll
        for (int mt = 0; mt < 4; mt++)
#pragma unroll
            for (int r = 0; r < 4; r++)
                o[(size_t)(m0 + mt * 16 + r) * HD_ + n0 + nt * 16] = acc[mt][nt][r];
}

// reduce 4 k-slice partials -> kvT[bh][d][f] bf16
__global__ __launch_bounds__(256) void k_kvred(const float* __restrict__ kvp, u16* __restrict__ kvT) {
    const int p = blockIdx.x, bh = blockIdx.y, t = threadIdx.x;
    const int e0 = p * 4096 + t * 16;
    float s[16];
#pragma unroll
    for (int i = 0; i < 16; i++) s[i] = 0.f;
    for (int c = 0; c < 4; c++) {
        const float* src = kvp + ((size_t)(c * 32 + bh)) * 32768 + e0;
#pragma unroll
        for (int i = 0; i < 16; i += 4) {
            float4 vv = *(const float4*)(src + i);
            s[i] += vv.x; s[i + 1] += vv.y; s[i + 2] += vv.z; s[i + 3] += vv.w;
        }
    }
#pragma unroll
    for (int i = 0; i < 16; i++) {
        int e = e0 + i, fq = e >> 7, d = e & 127;
        kvT[((size_t)bh * HD_ + d) * FD_ + fq] = f2bf(s[i]);
    }
}

// ---------------------------------------------------------------------------
// workspace layout (bytes), total ~237 MiB.  Launch order:
//   cvt -> transpose -> qkv -> feat<k> -> ksum2 -> gemm_kv -> kvred
//   -> feat<q>(attn fused) -> out
//   [0]          Wqkv_t 25,165,824 then Xbf 33,554,432 (dead after qkv)
//   [67108864]   kfT   67,108,864   ([bh][f][l])
//   [134217728]  qbuf  33,554,432   (live until feat<q>)
//   [167772160]  kbuf  33,554,432   -> kvp (16.8MB fp32, after feat<k>)
//                                   -> attn (after kvred consumes kvp)
//   [201326592]  vT    33,554,432   ([bh][d][l])
//   [234881024]  Wo_t   8,388,608
//   [243269632]  Wf1_t     65,536
//   [243335168]  Wf2_t    131,072
//   [243466240]  ksp    2,097,152
//   [245563392]  kvT    2,097,152
//   [247660544]  ksum      32,768   -> end 247,693,312
// ---------------------------------------------------------------------------
extern "C" void kernel_launch(void* const* d_in, const int* in_sizes, int n_in,
                              void* d_out, int out_size, void* d_ws, size_t ws_size,
                              hipStream_t stream) {
    const float* hs  = (const float*)d_in[0];
    const float* msk = (const float*)d_in[1];
    const float* Wq  = (const float*)d_in[2];  const float* bq  = (const float*)d_in[3];
    const float* Wk  = (const float*)d_in[4];  const float* bk  = (const float*)d_in[5];
    const float* Wv  = (const float*)d_in[6];  const float* bv  = (const float*)d_in[7];
    const float* Wo  = (const float*)d_in[8];  const float* bo  = (const float*)d_in[9];
    const float* Wf1 = (const float*)d_in[10]; const float* bf1 = (const float*)d_in[11];
    const float* Wf2 = (const float*)d_in[12]; const float* bf2 = (const float*)d_in[13];
    const float* lng = (const float*)d_in[14]; const float* lnb = (const float*)d_in[15];
    float* out = (float*)d_out;
    char* w = (char*)d_ws;

    u16* Wqkv_t = (u16*)(w + 0);               // dead after qkv
    u16* Xbf    = (u16*)(w + 25165824u);       // dead after qkv
    u16* kfT    = (u16*)(w + 67108864u);
    u16* qbuf   = (u16*)(w + 134217728u);
    u16* kbuf   = (u16*)(w + 167772160u);
    float* kvp  = (float*)(w + 167772160u);    // alias: kbuf dead after feat<k>
    u16* attn   = (u16*)(w + 167772160u);      // alias: kvp dead after kvred
    u16* vT     = (u16*)(w + 201326592u);
    u16* Wo_t   = (u16*)(w + 234881024u);
    u16* Wf1_t  = (u16*)(w + 243269632u);
    u16* Wf2_t  = (u16*)(w + 243335168u);
    float* ksp  = (float*)(w + 243466240u);
    u16* kvT    = (u16*)(w + 245563392u);
    float* ksum = (float*)(w + 247660544u);

    k_cvt<<<dim3(8192), 256, 0, stream>>>(hs, Xbf);
    k_transpose<<<dim3(64, 64, 6), dim3(32, 8), 0, stream>>>(Wq, Wk, Wv, Wo, Wf1, Wf2,
                                                             Wqkv_t, Wo_t, Wf1_t, Wf2_t);
    k_gemm_qkv<<<dim3(768), 512, 0, stream>>>(Xbf, Wqkv_t, bq, bk, bv, qbuf, kbuf, vT);
    // k-chain first so ksum + kvT are ready before feat<q> (attn fused there)
    k_feat<1, 1><<<dim3(2048), 256, 0, stream>>>(kbuf, Wf1_t, bf1, Wf2_t, bf2, lng, lnb, msk,
                                                 nullptr, nullptr, kfT, ksp, nullptr);
    k_ksum2<<<dim3(32), 256, 0, stream>>>(ksp, ksum);
    k_gemm_kv<<<dim3(2, 4, 32), 256, 0, stream>>>(kfT, vT, kvp);
    k_kvred<<<dim3(8, 32), 256, 0, stream>>>(kvp, kvT);
    k_feat<0, 0><<<dim3(2048), 256, 0, stream>>>(qbuf, Wf1_t, bf1, Wf2_t, bf2, lng, lnb, msk,
                                                 ksum, kvT, nullptr, nullptr, attn);
    k_gemm_out<<<dim3(256), 512, 0, stream>>>(attn, Wo_t, bo, out);
}